// Round 1
// baseline (567.637 us; speedup 1.0000x reference)
//
#include <hip/hip_runtime.h>
#include <hip/hip_bf16.h>

typedef short bf16x8 __attribute__((ext_vector_type(8)));
typedef float f32x4 __attribute__((ext_vector_type(4)));

#define MFMA16(a, b, c) __builtin_amdgcn_mfma_f32_16x16x32_bf16((a), (b), (c), 0, 0, 0)

static __device__ __forceinline__ unsigned short f2bf(float f) {
  union { float f; unsigned u; } v;
  v.f = f;
  unsigned r = (v.u + 0x7FFFu + ((v.u >> 16) & 1u)) >> 16;
  return (unsigned short)r;
}

static __device__ __forceinline__ void gload16(const void* g, void* l) {
  __builtin_amdgcn_global_load_lds(
      (const __attribute__((address_space(1))) unsigned int*)g,
      (__attribute__((address_space(3))) unsigned int*)l, 16, 0, 0);
}

// ---------------- cast f32 -> bf16 (vectorized) ----------------
__global__ __launch_bounds__(256) void cast_f32_bf16(
    const float* __restrict__ src, unsigned short* __restrict__ dst, int n4) {
  int stride = gridDim.x * blockDim.x;
  for (int i = blockIdx.x * blockDim.x + threadIdx.x; i < n4; i += stride) {
    float4 v = reinterpret_cast<const float4*>(src)[i];
    ushort4 o;
    o.x = f2bf(v.x); o.y = f2bf(v.y); o.z = f2bf(v.z); o.w = f2bf(v.w);
    reinterpret_cast<ushort4*>(dst)[i] = o;
  }
}

// ---------------- transpose + cast: src[R][C] f32 -> dst[C][R] bf16 ----------------
__global__ __launch_bounds__(256) void transpose_cast(
    const float* __restrict__ src, unsigned short* __restrict__ dst, int R, int C) {
  __shared__ float tile[32][33];
  int tx = threadIdx.x & 31;
  int ty = threadIdx.x >> 5;  // 0..7
  int r0 = blockIdx.y * 32, c0 = blockIdx.x * 32;
#pragma unroll
  for (int i = 0; i < 32; i += 8)
    tile[ty + i][tx] = src[(size_t)(r0 + ty + i) * C + (c0 + tx)];
  __syncthreads();
#pragma unroll
  for (int i = 0; i < 32; i += 8)
    dst[(size_t)(c0 + ty + i) * R + (r0 + tx)] = f2bf(tile[tx][ty + i]);
}

// ---------------- GEMM: C[M,N] = A[M,K] * B[N,K]^T  (bf16 in, bf16 or f32+bias out) ----------------
// 128x128 tile, BK=32, 4 waves (each 64x64 = 4x4 frags of 16x16), global_load_lds staging.
template <int EPI>
__global__ __launch_bounds__(256) void gemm_bt(
    const unsigned short* __restrict__ A, const unsigned short* __restrict__ B,
    unsigned short* __restrict__ Cb, float* __restrict__ Cf,
    const float* __restrict__ bias, int M, int N, int K) {
  __shared__ unsigned short Asm[128 * 32];
  __shared__ unsigned short Bsm[128 * 32];
  const int tid = threadIdx.x;
  const int wave = tid >> 6;
  const int lane = tid & 63;
  const int l15 = lane & 15, l4 = lane >> 4;
  const int tilesN = N >> 7;
  const int bm = blockIdx.x / tilesN, bn = blockIdx.x % tilesN;
  const int row0 = bm << 7, col0 = bn << 7;
  const int wr = (wave >> 1) << 6, wc = (wave & 1) << 6;

  // staging geometry: 512 chunks of 16B per 128x32 tile; 2 wave-level calls per wave.
  const int ch0 = wave * 128 + lane;
  const int ch1 = ch0 + 64;
  const int r_a0 = ch0 >> 2, k_a0 = (ch0 & 3) * 8;
  const int r_a1 = ch1 >> 2, k_a1 = (ch1 & 3) * 8;

  f32x4 acc[4][4] = {};

  for (int kt = 0; kt < K; kt += 32) {
    if (kt) __syncthreads();
    gload16(A + (size_t)(row0 + r_a0) * K + kt + k_a0, &Asm[(wave * 2 + 0) * 512]);
    gload16(A + (size_t)(row0 + r_a1) * K + kt + k_a1, &Asm[(wave * 2 + 1) * 512]);
    gload16(B + (size_t)(col0 + r_a0) * K + kt + k_a0, &Bsm[(wave * 2 + 0) * 512]);
    gload16(B + (size_t)(col0 + r_a1) * K + kt + k_a1, &Bsm[(wave * 2 + 1) * 512]);
    __syncthreads();

    bf16x8 af[4], bvf[4];
#pragma unroll
    for (int m = 0; m < 4; ++m)
      af[m] = *(const bf16x8*)&Asm[(wr + m * 16 + l15) * 32 + l4 * 8];
#pragma unroll
    for (int n = 0; n < 4; ++n)
      bvf[n] = *(const bf16x8*)&Bsm[(wc + n * 16 + l15) * 32 + l4 * 8];
#pragma unroll
    for (int m = 0; m < 4; ++m)
#pragma unroll
      for (int n = 0; n < 4; ++n)
        acc[m][n] = MFMA16(af[m], bvf[n], acc[m][n]);
  }

#pragma unroll
  for (int m = 0; m < 4; ++m) {
#pragma unroll
    for (int n = 0; n < 4; ++n) {
      int row = row0 + wr + m * 16 + l4 * 4;
      int col = col0 + wc + n * 16 + l15;
#pragma unroll
      for (int r = 0; r < 4; ++r) {
        if (EPI == 0) {
          Cb[(size_t)(row + r) * N + col] = f2bf(acc[m][n][r]);
        } else {
          Cf[(size_t)(row + r) * N + col] = acc[m][n][r] + bias[col];
        }
      }
    }
  }
}

// ---------------- flash attention (causal, GQA) ----------------
// 1 wave per 16 query rows. KVBLK=32. Q/K: [b,n,*] bf16 row-major; V: transposed [512, 4096].
// Ctx out: [b,n,2048] bf16 (channel layout h*128+d == (g,s,d)).
__global__ __launch_bounds__(64) void flash_gqa(
    const unsigned short* __restrict__ Qb, const unsigned short* __restrict__ Kb,
    const unsigned short* __restrict__ VT, unsigned short* __restrict__ Ctx) {
  __shared__ unsigned short plds[16 * 32];
  const int lane = threadIdx.x;
  const int l15 = lane & 15, l4 = lane >> 4;
  const int qt = blockIdx.x;  // 0..127
  const int bh = blockIdx.y;  // 0..31
  const int b = bh >> 4, h = bh & 15;
  const int g = h >> 2;
  const int q0 = qt << 4;

  // Q fragments (A-operand), held for the whole block
  const unsigned short* qptr =
      Qb + (size_t)(b * 2048 + q0 + l15) * 2048 + h * 128 + l4 * 8;
  bf16x8 qf[4];
#pragma unroll
  for (int ks = 0; ks < 4; ++ks) qf[ks] = *(const bf16x8*)(qptr + ks * 32);

  const unsigned short* kbase = Kb + (size_t)(b * 2048) * 512 + g * 128;
  const unsigned short* vbase = VT + (size_t)(g * 128) * 4096 + (size_t)b * 2048;

  float m_r[4], l_r[4];
#pragma unroll
  for (int r = 0; r < 4; ++r) { m_r[r] = -1e30f; l_r[r] = 0.f; }
  f32x4 o[8] = {};

  const float scale = 0.08838834764831845f;  // 1/sqrt(128)
  const int kv_end = q0 + 16;
  for (int kv = 0; kv < kv_end; kv += 32) {
    // ---- S = Q K^T (16 x 32), two 16-col tiles ----
    f32x4 s[2];
#pragma unroll
    for (int ct = 0; ct < 2; ++ct) {
      const unsigned short* kp = kbase + (size_t)(kv + ct * 16 + l15) * 512 + l4 * 8;
      f32x4 a = {0.f, 0.f, 0.f, 0.f};
#pragma unroll
      for (int ks = 0; ks < 4; ++ks) {
        bf16x8 kf = *(const bf16x8*)(kp + ks * 32);
        a = MFMA16(qf[ks], kf, a);
      }
      s[ct] = a;
    }
    // ---- scale + causal mask (keep k <= q) ----
    const int qrb = q0 + l4 * 4;
#pragma unroll
    for (int ct = 0; ct < 2; ++ct) {
      const int kc = kv + ct * 16 + l15;
#pragma unroll
      for (int r = 0; r < 4; ++r) {
        float v = s[ct][r] * scale;
        s[ct][r] = (kc <= qrb + r) ? v : -1e30f;
      }
    }
    // ---- row max across 32 cols (2 in-lane + 16-lane xor reduce) ----
    float pm[4];
#pragma unroll
    for (int r = 0; r < 4; ++r) pm[r] = fmaxf(s[0][r], s[1][r]);
#pragma unroll
    for (int off = 1; off < 16; off <<= 1)
#pragma unroll
      for (int r = 0; r < 4; ++r) pm[r] = fmaxf(pm[r], __shfl_xor(pm[r], off, 64));
    // ---- online softmax update ----
    float osc[4], p[2][4], psum[4];
#pragma unroll
    for (int r = 0; r < 4; ++r) {
      float mn = fmaxf(m_r[r], pm[r]);
      osc[r] = __expf(m_r[r] - mn);
      m_r[r] = mn;
      l_r[r] *= osc[r];
      psum[r] = 0.f;
    }
#pragma unroll
    for (int dt = 0; dt < 8; ++dt)
#pragma unroll
      for (int r = 0; r < 4; ++r) o[dt][r] *= osc[r];
#pragma unroll
    for (int ct = 0; ct < 2; ++ct)
#pragma unroll
      for (int r = 0; r < 4; ++r) {
        float pe = __expf(s[ct][r] - m_r[r]);
        p[ct][r] = pe;
        psum[r] += pe;
      }
#pragma unroll
    for (int off = 1; off < 16; off <<= 1)
#pragma unroll
      for (int r = 0; r < 4; ++r) psum[r] += __shfl_xor(psum[r], off, 64);
#pragma unroll
    for (int r = 0; r < 4; ++r) l_r[r] += psum[r];
    // ---- P (C-layout) -> LDS -> A-fragment (transpose), single-wave so no barrier ----
#pragma unroll
    for (int ct = 0; ct < 2; ++ct)
#pragma unroll
      for (int r = 0; r < 4; ++r)
        plds[(l4 * 4 + r) * 32 + ct * 16 + l15] = f2bf(p[ct][r]);
    bf16x8 pf = *(const bf16x8*)&plds[l15 * 32 + l4 * 8];
    // ---- O += P V : 8 dv-tiles of 16, V^T rows are contiguous along kv ----
#pragma unroll
    for (int dt = 0; dt < 8; ++dt) {
      const unsigned short* vp = vbase + (size_t)(dt * 16 + l15) * 4096 + kv + l4 * 8;
      bf16x8 vf = *(const bf16x8*)vp;
      o[dt] = MFMA16(pf, vf, o[dt]);
    }
  }
  // ---- finalize: divide by l, write ctx ----
  float inv[4];
#pragma unroll
  for (int r = 0; r < 4; ++r) inv[r] = 1.f / l_r[r];
  unsigned short* cp = Ctx + (size_t)(b * 2048 + q0 + l4 * 4) * 2048 + h * 128;
#pragma unroll
  for (int dt = 0; dt < 8; ++dt)
#pragma unroll
    for (int r = 0; r < 4; ++r)
      cp[(size_t)r * 2048 + dt * 16 + l15] = f2bf(o[dt][r] * inv[r]);
}

// ---------------- launch ----------------
extern "C" void kernel_launch(void* const* d_in, const int* in_sizes, int n_in,
                              void* d_out, int out_size, void* d_ws, size_t ws_size,
                              hipStream_t stream) {
  (void)in_sizes; (void)n_in; (void)out_size; (void)ws_size;
  const float* x  = (const float*)d_in[0];
  const float* Wq = (const float*)d_in[1];
  const float* Wk = (const float*)d_in[2];
  const float* Wv = (const float*)d_in[3];
  const float* Wo = (const float*)d_in[4];
  const float* bo = (const float*)d_in[5];
  float* out = (float*)d_out;

  unsigned short* Xb  = (unsigned short*)d_ws;            // [4096,2048]
  unsigned short* WqT = Xb  + (size_t)4096 * 2048;        // [2048,2048]
  unsigned short* WkT = WqT + (size_t)2048 * 2048;        // [512,2048]
  unsigned short* WvT = WkT + (size_t)512 * 2048;         // [512,2048]
  unsigned short* WoT = WvT + (size_t)512 * 2048;         // [2048,2048]
  unsigned short* Qb  = WoT + (size_t)2048 * 2048;        // [4096,2048]
  unsigned short* Kb  = Qb  + (size_t)4096 * 2048;        // [4096,512]
  unsigned short* VTb = Kb  + (size_t)4096 * 512;         // [512,4096]
  unsigned short* Ctx = VTb + (size_t)512 * 4096;         // [4096,2048]

  cast_f32_bf16<<<2048, 256, 0, stream>>>(x, Xb, (4096 * 2048) / 4);
  transpose_cast<<<dim3(64, 64), 256, 0, stream>>>(Wq, WqT, 2048, 2048);
  transpose_cast<<<dim3(16, 64), 256, 0, stream>>>(Wk, WkT, 2048, 512);
  transpose_cast<<<dim3(16, 64), 256, 0, stream>>>(Wv, WvT, 2048, 512);
  transpose_cast<<<dim3(64, 64), 256, 0, stream>>>(Wo, WoT, 2048, 2048);

  // Q = x Wq : [4096,2048]
  gemm_bt<0><<<dim3(512), 256, 0, stream>>>(Xb, WqT, Qb, nullptr, nullptr, 4096, 2048, 2048);
  // K = x Wk : [4096,512]
  gemm_bt<0><<<dim3(128), 256, 0, stream>>>(Xb, WkT, Kb, nullptr, nullptr, 4096, 512, 2048);
  // V^T = Wv^T x^T : [512,4096]
  gemm_bt<0><<<dim3(128), 256, 0, stream>>>(WvT, Xb, VTb, nullptr, nullptr, 512, 4096, 2048);

  flash_gqa<<<dim3(128, 32), 64, 0, stream>>>(Qb, Kb, VTb, Ctx);

  // out = ctx Wo + bo : [4096,2048] f32
  gemm_bt<1><<<dim3(512), 256, 0, stream>>>(Ctx, WoT, nullptr, out, bo, 4096, 2048, 2048);
}

// Round 2
// 452.702 us; speedup vs baseline: 1.2539x; 1.2539x over previous
//
#include <hip/hip_runtime.h>
#include <hip/hip_bf16.h>

typedef short bf16x8 __attribute__((ext_vector_type(8)));
typedef float f32x4 __attribute__((ext_vector_type(4)));

#define MFMA16(a, b, c) __builtin_amdgcn_mfma_f32_16x16x32_bf16((a), (b), (c), 0, 0, 0)

static __device__ __forceinline__ unsigned short f2bf(float f) {
  union { float f; unsigned u; } v;
  v.f = f;
  unsigned r = (v.u + 0x7FFFu + ((v.u >> 16) & 1u)) >> 16;
  return (unsigned short)r;
}

static __device__ __forceinline__ void gload16(const void* g, void* l) {
  __builtin_amdgcn_global_load_lds(
      (const __attribute__((address_space(1))) unsigned int*)g,
      (__attribute__((address_space(3))) unsigned int*)l, 16, 0, 0);
}

// ---------------- cast f32 -> bf16 (vectorized) ----------------
__global__ __launch_bounds__(256) void cast_f32_bf16(
    const float* __restrict__ src, unsigned short* __restrict__ dst, int n4) {
  int stride = gridDim.x * blockDim.x;
  for (int i = blockIdx.x * blockDim.x + threadIdx.x; i < n4; i += stride) {
    float4 v = reinterpret_cast<const float4*>(src)[i];
    ushort4 o;
    o.x = f2bf(v.x); o.y = f2bf(v.y); o.z = f2bf(v.z); o.w = f2bf(v.w);
    reinterpret_cast<ushort4*>(dst)[i] = o;
  }
}

// ---------------- transpose + cast: src[R][C] f32 -> dst[C][R] bf16 ----------------
__global__ __launch_bounds__(256) void transpose_cast(
    const float* __restrict__ src, unsigned short* __restrict__ dst, int R, int C) {
  __shared__ float tile[32][33];
  int tx = threadIdx.x & 31;
  int ty = threadIdx.x >> 5;  // 0..7
  int r0 = blockIdx.y * 32, c0 = blockIdx.x * 32;
#pragma unroll
  for (int i = 0; i < 32; i += 8)
    tile[ty + i][tx] = src[(size_t)(r0 + ty + i) * C + (c0 + tx)];
  __syncthreads();
#pragma unroll
  for (int i = 0; i < 32; i += 8)
    dst[(size_t)(c0 + ty + i) * R + (r0 + tx)] = f2bf(tile[tx][ty + i]);
}

// ---------------- GEMM: C[M,N] = A[M,K] * B[N,K]^T  (bf16 in, bf16 or f32+bias out) ----------------
template <int EPI>
__global__ __launch_bounds__(256) void gemm_bt(
    const unsigned short* __restrict__ A, const unsigned short* __restrict__ B,
    unsigned short* __restrict__ Cb, float* __restrict__ Cf,
    const float* __restrict__ bias, int M, int N, int K) {
  __shared__ unsigned short Asm[128 * 32];
  __shared__ unsigned short Bsm[128 * 32];
  const int tid = threadIdx.x;
  const int wave = tid >> 6;
  const int lane = tid & 63;
  const int l15 = lane & 15, l4 = lane >> 4;
  const int tilesN = N >> 7;
  const int bm = blockIdx.x / tilesN, bn = blockIdx.x % tilesN;
  const int row0 = bm << 7, col0 = bn << 7;
  const int wr = (wave >> 1) << 6, wc = (wave & 1) << 6;

  const int ch0 = wave * 128 + lane;
  const int ch1 = ch0 + 64;
  const int r_a0 = ch0 >> 2, k_a0 = (ch0 & 3) * 8;
  const int r_a1 = ch1 >> 2, k_a1 = (ch1 & 3) * 8;

  f32x4 acc[4][4] = {};

  for (int kt = 0; kt < K; kt += 32) {
    if (kt) __syncthreads();
    gload16(A + (size_t)(row0 + r_a0) * K + kt + k_a0, &Asm[(wave * 2 + 0) * 512]);
    gload16(A + (size_t)(row0 + r_a1) * K + kt + k_a1, &Asm[(wave * 2 + 1) * 512]);
    gload16(B + (size_t)(col0 + r_a0) * K + kt + k_a0, &Bsm[(wave * 2 + 0) * 512]);
    gload16(B + (size_t)(col0 + r_a1) * K + kt + k_a1, &Bsm[(wave * 2 + 1) * 512]);
    __syncthreads();

    bf16x8 af[4], bvf[4];
#pragma unroll
    for (int m = 0; m < 4; ++m)
      af[m] = *(const bf16x8*)&Asm[(wr + m * 16 + l15) * 32 + l4 * 8];
#pragma unroll
    for (int n = 0; n < 4; ++n)
      bvf[n] = *(const bf16x8*)&Bsm[(wc + n * 16 + l15) * 32 + l4 * 8];
#pragma unroll
    for (int m = 0; m < 4; ++m)
#pragma unroll
      for (int n = 0; n < 4; ++n)
        acc[m][n] = MFMA16(af[m], bvf[n], acc[m][n]);
  }

#pragma unroll
  for (int m = 0; m < 4; ++m) {
#pragma unroll
    for (int n = 0; n < 4; ++n) {
      int row = row0 + wr + m * 16 + l4 * 4;
      int col = col0 + wc + n * 16 + l15;
#pragma unroll
      for (int r = 0; r < 4; ++r) {
        if (EPI == 0) {
          Cb[(size_t)(row + r) * N + col] = f2bf(acc[m][n][r]);
        } else {
          Cf[(size_t)(row + r) * N + col] = acc[m][n][r] + bias[col];
        }
      }
    }
  }
}

// ---------------- flash attention v2 (causal, GQA) ----------------
// 512 threads = 8 waves. Block = (b, g, q-tile pair {qt, 127-qt}).
// Waves 0-3: heads 0-3 of tile A (qt=pair); waves 4-7: heads 0-3 of tile B (qt=127-pair).
// K/V staged in LDS per KV step (KVBLK=64), shared by all 8 waves.
// XOR chunk swizzle (byte ^= (row&7)<<4) via pre-swizzled global source (rule #21).
__global__ __launch_bounds__(512, 4) void flash_gqa2(
    const unsigned short* __restrict__ Qb, const unsigned short* __restrict__ Kb,
    const unsigned short* __restrict__ VT, unsigned short* __restrict__ Ctx) {
  __shared__ unsigned short Ksm[64 * 128];   // [kv][d], swizzled 16B chunks
  __shared__ unsigned short Vsm[128 * 64];   // [dv][kv], swizzled
  __shared__ unsigned short Psm[8 * 16 * 64];  // per-wave [16][64], swizzled

  const int tid = threadIdx.x;
  const int wave = tid >> 6, lane = tid & 63;
  const int l15 = lane & 15, l4 = lane >> 4;
  const int pair = blockIdx.x;  // 0..63
  const int bg = blockIdx.y;    // 0..7
  const int b = bg >> 2, g = bg & 3;
  const int h = (g << 2) | (wave & 3);
  const int qt = (wave < 4) ? pair : (127 - pair);
  const int q0 = qt << 4;
  const int kv_my_end = q0 + 16;
  const int kv_end = 2048 - pair * 16;  // tile B's end (the max of the two)

  // Q fragments (A-operand), held for the whole block
  const unsigned short* qptr =
      Qb + (size_t)(b * 2048 + q0 + l15) * 2048 + h * 128 + l4 * 8;
  bf16x8 qf[4];
#pragma unroll
  for (int ks = 0; ks < 4; ++ks) qf[ks] = *(const bf16x8*)(qptr + ks * 32);

  // --- staging thread-constants (pre-swizzled global source) ---
  // K tile: 1024 chunks of 16B; chunk q = tid + call*512; row=q>>4 (kv), c=q&15.
  const int qa = tid, qb2 = tid + 512;
  const int rK0 = qa >> 4, cK0 = qa & 15;
  const int rK1 = qb2 >> 4, cK1 = qb2 & 15;
  const unsigned short* kSrc0 =
      Kb + (size_t)(b * 2048 + rK0) * 512 + g * 128 + (cK0 ^ (rK0 & 7)) * 8;
  const unsigned short* kSrc1 =
      Kb + (size_t)(b * 2048 + rK1) * 512 + g * 128 + (cK1 ^ (rK1 & 7)) * 8;
  // V tile: [dv=128][kv=64]; chunk q: row=q>>3 (dv), c=q&7.
  const int rV0 = qa >> 3, cV0 = qa & 7;
  const int rV1 = qb2 >> 3, cV1 = qb2 & 7;
  const unsigned short* vSrc0 =
      VT + (size_t)(g * 128 + rV0) * 4096 + b * 2048 + (cV0 ^ (rV0 & 7)) * 8;
  const unsigned short* vSrc1 =
      VT + (size_t)(g * 128 + rV1) * 4096 + b * 2048 + (cV1 ^ (rV1 & 7)) * 8;
  // LDS dests (wave-uniform base; HW adds lane*16)
  unsigned short* kDst0 = &Ksm[(size_t)wave * 64 * 8];
  unsigned short* kDst1 = &Ksm[(size_t)(512 + wave * 64) * 8];
  unsigned short* vDst0 = &Vsm[(size_t)wave * 64 * 8];
  unsigned short* vDst1 = &Vsm[(size_t)(512 + wave * 64) * 8];
  char* pbase = (char*)&Psm[(size_t)wave * 16 * 64];

  float m_r[4], l_r[4];
#pragma unroll
  for (int r = 0; r < 4; ++r) { m_r[r] = -1e30f; l_r[r] = 0.f; }
  f32x4 o[8] = {};

  const float scale = 0.08838834764831845f;  // 1/sqrt(128)

  for (int kv = 0; kv < kv_end; kv += 64) {
    if (kv) __syncthreads();
    // ---- stage K[kv..kv+64)[128] and V^T[128][kv..kv+64) ----
    gload16(kSrc0 + (size_t)kv * 512, kDst0);
    gload16(kSrc1 + (size_t)kv * 512, kDst1);
    gload16(vSrc0 + kv, vDst0);
    gload16(vSrc1 + kv, vDst1);
    __syncthreads();  // emits vmcnt(0) drain -> staging complete

    if (kv < kv_my_end) {
      // ---- S = Q K^T : 16 rows x 64 cols, 4 col-tiles ----
      f32x4 s[4];
#pragma unroll
      for (int ct = 0; ct < 4; ++ct) {
        f32x4 a = {0.f, 0.f, 0.f, 0.f};
#pragma unroll
        for (int ks = 0; ks < 4; ++ks) {
          const int row = ct * 16 + l15;
          int byte = row * 256 + ks * 64 + l4 * 16;
          byte ^= (row & 7) << 4;
          bf16x8 kf = *(const bf16x8*)((const char*)Ksm + byte);
          a = MFMA16(qf[ks], kf, a);
        }
        s[ct] = a;
      }
      // ---- scale + causal mask ----
      const int qrb = q0 + l4 * 4;
      if (kv + 64 > q0) {
#pragma unroll
        for (int ct = 0; ct < 4; ++ct) {
          const int kc = kv + ct * 16 + l15;
#pragma unroll
          for (int r = 0; r < 4; ++r) {
            float v = s[ct][r] * scale;
            s[ct][r] = (kc <= qrb + r) ? v : -1e30f;
          }
        }
      } else {
#pragma unroll
        for (int ct = 0; ct < 4; ++ct)
#pragma unroll
          for (int r = 0; r < 4; ++r) s[ct][r] *= scale;
      }
      // ---- row max (4 in-lane + 16-lane xor reduce) ----
      float pm[4];
#pragma unroll
      for (int r = 0; r < 4; ++r)
        pm[r] = fmaxf(fmaxf(s[0][r], s[1][r]), fmaxf(s[2][r], s[3][r]));
#pragma unroll
      for (int off = 1; off < 16; off <<= 1)
#pragma unroll
        for (int r = 0; r < 4; ++r) pm[r] = fmaxf(pm[r], __shfl_xor(pm[r], off, 64));
      // ---- online softmax update ----
      float osc[4], psum[4];
#pragma unroll
      for (int r = 0; r < 4; ++r) {
        float mn = fmaxf(m_r[r], pm[r]);
        osc[r] = __expf(m_r[r] - mn);
        m_r[r] = mn;
        l_r[r] *= osc[r];
        psum[r] = 0.f;
      }
#pragma unroll
      for (int dt = 0; dt < 8; ++dt)
#pragma unroll
        for (int r = 0; r < 4; ++r) o[dt][r] *= osc[r];
      // ---- P = exp(S - m), write to per-wave LDS (swizzled), row-sum ----
#pragma unroll
      for (int ct = 0; ct < 4; ++ct) {
#pragma unroll
        for (int r = 0; r < 4; ++r) {
          float pe = __expf(s[ct][r] - m_r[r]);
          psum[r] += pe;
          const int prow = l4 * 4 + r;
          int byte = prow * 128 + (ct * 16 + l15) * 2;
          byte ^= (prow & 7) << 4;
          *(unsigned short*)(pbase + byte) = f2bf(pe);
        }
      }
#pragma unroll
      for (int off = 1; off < 16; off <<= 1)
#pragma unroll
        for (int r = 0; r < 4; ++r) psum[r] += __shfl_xor(psum[r], off, 64);
#pragma unroll
      for (int r = 0; r < 4; ++r) l_r[r] += psum[r];
      // ---- O += P V : read P A-frags (swizzled), V B-frags (swizzled) ----
      bf16x8 pf[2];
#pragma unroll
      for (int ks2 = 0; ks2 < 2; ++ks2) {
        int byte = l15 * 128 + ks2 * 64 + l4 * 16;
        byte ^= (l15 & 7) << 4;
        pf[ks2] = *(const bf16x8*)(pbase + byte);
      }
#pragma unroll
      for (int dt = 0; dt < 8; ++dt) {
#pragma unroll
        for (int ks2 = 0; ks2 < 2; ++ks2) {
          const int row = dt * 16 + l15;
          int byte = row * 128 + ks2 * 64 + l4 * 16;
          byte ^= (row & 7) << 4;
          bf16x8 vf = *(const bf16x8*)((const char*)Vsm + byte);
          o[dt] = MFMA16(pf[ks2], vf, o[dt]);
        }
      }
    }
  }
  // ---- finalize ----
  float inv[4];
#pragma unroll
  for (int r = 0; r < 4; ++r) inv[r] = 1.f / l_r[r];
  unsigned short* cp = Ctx + (size_t)(b * 2048 + q0 + l4 * 4) * 2048 + h * 128;
#pragma unroll
  for (int dt = 0; dt < 8; ++dt)
#pragma unroll
    for (int r = 0; r < 4; ++r)
      cp[(size_t)r * 2048 + dt * 16 + l15] = f2bf(o[dt][r] * inv[r]);
}

// ---------------- launch ----------------
extern "C" void kernel_launch(void* const* d_in, const int* in_sizes, int n_in,
                              void* d_out, int out_size, void* d_ws, size_t ws_size,
                              hipStream_t stream) {
  (void)in_sizes; (void)n_in; (void)out_size; (void)ws_size;
  const float* x  = (const float*)d_in[0];
  const float* Wq = (const float*)d_in[1];
  const float* Wk = (const float*)d_in[2];
  const float* Wv = (const float*)d_in[3];
  const float* Wo = (const float*)d_in[4];
  const float* bo = (const float*)d_in[5];
  float* out = (float*)d_out;

  unsigned short* Xb  = (unsigned short*)d_ws;            // [4096,2048]
  unsigned short* WqT = Xb  + (size_t)4096 * 2048;        // [2048,2048]
  unsigned short* WkT = WqT + (size_t)2048 * 2048;        // [512,2048]
  unsigned short* WvT = WkT + (size_t)512 * 2048;         // [512,2048]
  unsigned short* WoT = WvT + (size_t)512 * 2048;         // [2048,2048]
  unsigned short* Qb  = WoT + (size_t)2048 * 2048;        // [4096,2048]
  unsigned short* Kb  = Qb  + (size_t)4096 * 2048;        // [4096,512]
  unsigned short* VTb = Kb  + (size_t)4096 * 512;         // [512,4096]
  unsigned short* Ctx = VTb + (size_t)512 * 4096;         // [4096,2048]

  cast_f32_bf16<<<2048, 256, 0, stream>>>(x, Xb, (4096 * 2048) / 4);
  transpose_cast<<<dim3(64, 64), 256, 0, stream>>>(Wq, WqT, 2048, 2048);
  transpose_cast<<<dim3(16, 64), 256, 0, stream>>>(Wk, WkT, 2048, 512);
  transpose_cast<<<dim3(16, 64), 256, 0, stream>>>(Wv, WvT, 2048, 512);
  transpose_cast<<<dim3(64, 64), 256, 0, stream>>>(Wo, WoT, 2048, 2048);

  // Q = x Wq : [4096,2048]
  gemm_bt<0><<<dim3(512), 256, 0, stream>>>(Xb, WqT, Qb, nullptr, nullptr, 4096, 2048, 2048);
  // K = x Wk : [4096,512]
  gemm_bt<0><<<dim3(128), 256, 0, stream>>>(Xb, WkT, Kb, nullptr, nullptr, 4096, 512, 2048);
  // V^T = Wv^T x^T : [512,4096]
  gemm_bt<0><<<dim3(128), 256, 0, stream>>>(WvT, Xb, VTb, nullptr, nullptr, 512, 4096, 2048);

  flash_gqa2<<<dim3(64, 8), 512, 0, stream>>>(Qb, Kb, VTb, Ctx);

  // out = ctx Wo + bo : [4096,2048] f32
  gemm_bt<1><<<dim3(512), 256, 0, stream>>>(Ctx, WoT, nullptr, out, bo, 4096, 2048, 2048);
}

// Round 3
// 232.951 us; speedup vs baseline: 2.4367x; 1.9433x over previous
//
#include <hip/hip_runtime.h>
#include <hip/hip_bf16.h>

typedef short bf16x8 __attribute__((ext_vector_type(8)));
typedef float f32x4 __attribute__((ext_vector_type(4)));
typedef float f32x16 __attribute__((ext_vector_type(16)));
typedef unsigned int u32x4 __attribute__((ext_vector_type(4)));

#define MFMA16(a, b, c) __builtin_amdgcn_mfma_f32_16x16x32_bf16((a), (b), (c), 0, 0, 0)
#define MFMA32(a, b, c) __builtin_amdgcn_mfma_f32_32x32x16_bf16((a), (b), (c), 0, 0, 0)

static __device__ __forceinline__ unsigned short f2bf(float f) {
  union { float f; unsigned u; } v;
  v.f = f;
  unsigned r = (v.u + 0x7FFFu + ((v.u >> 16) & 1u)) >> 16;
  return (unsigned short)r;
}

static __device__ __forceinline__ void gload16(const void* g, void* l) {
  __builtin_amdgcn_global_load_lds(
      (const __attribute__((address_space(1))) unsigned int*)g,
      (__attribute__((address_space(3))) unsigned int*)l, 16, 0, 0);
}

// ---------------- cast f32 -> bf16 (vectorized) ----------------
__global__ __launch_bounds__(256) void cast_f32_bf16(
    const float* __restrict__ src, unsigned short* __restrict__ dst, int n4) {
  int stride = gridDim.x * blockDim.x;
  for (int i = blockIdx.x * blockDim.x + threadIdx.x; i < n4; i += stride) {
    float4 v = reinterpret_cast<const float4*>(src)[i];
    ushort4 o;
    o.x = f2bf(v.x); o.y = f2bf(v.y); o.z = f2bf(v.z); o.w = f2bf(v.w);
    reinterpret_cast<ushort4*>(dst)[i] = o;
  }
}

// ---------------- transpose + cast: src[R][C] f32 -> dst[C][R] bf16 ----------------
__global__ __launch_bounds__(256) void transpose_cast(
    const float* __restrict__ src, unsigned short* __restrict__ dst, int R, int C) {
  __shared__ float tile[32][33];
  int tx = threadIdx.x & 31;
  int ty = threadIdx.x >> 5;  // 0..7
  int r0 = blockIdx.y * 32, c0 = blockIdx.x * 32;
#pragma unroll
  for (int i = 0; i < 32; i += 8)
    tile[ty + i][tx] = src[(size_t)(r0 + ty + i) * C + (c0 + tx)];
  __syncthreads();
#pragma unroll
  for (int i = 0; i < 32; i += 8)
    dst[(size_t)(c0 + ty + i) * R + (r0 + tx)] = f2bf(tile[tx][ty + i]);
}

// ---------------- GEMM core: C[M,N] = A[M,K] * B[N,K]^T ----------------
template <int EPI>
static __device__ __forceinline__ void gemm_core(
    unsigned short* Asm, unsigned short* Bsm,
    const unsigned short* __restrict__ A, const unsigned short* __restrict__ B,
    unsigned short* __restrict__ Cb, float* __restrict__ Cf,
    const float* __restrict__ bias, int N, int K, int bid) {
  const int tid = threadIdx.x;
  const int wave = tid >> 6;
  const int lane = tid & 63;
  const int l15 = lane & 15, l4 = lane >> 4;
  const int tilesN = N >> 7;
  const int bm = bid / tilesN, bn = bid % tilesN;
  const int row0 = bm << 7, col0 = bn << 7;
  const int wr = (wave >> 1) << 6, wc = (wave & 1) << 6;

  const int ch0 = wave * 128 + lane;
  const int ch1 = ch0 + 64;
  const int r_a0 = ch0 >> 2, k_a0 = (ch0 & 3) * 8;
  const int r_a1 = ch1 >> 2, k_a1 = (ch1 & 3) * 8;

  f32x4 acc[4][4] = {};

  for (int kt = 0; kt < K; kt += 32) {
    if (kt) __syncthreads();
    gload16(A + (size_t)(row0 + r_a0) * K + kt + k_a0, &Asm[(wave * 2 + 0) * 512]);
    gload16(A + (size_t)(row0 + r_a1) * K + kt + k_a1, &Asm[(wave * 2 + 1) * 512]);
    gload16(B + (size_t)(col0 + r_a0) * K + kt + k_a0, &Bsm[(wave * 2 + 0) * 512]);
    gload16(B + (size_t)(col0 + r_a1) * K + kt + k_a1, &Bsm[(wave * 2 + 1) * 512]);
    __syncthreads();

    bf16x8 af[4], bvf[4];
#pragma unroll
    for (int m = 0; m < 4; ++m)
      af[m] = *(const bf16x8*)&Asm[(wr + m * 16 + l15) * 32 + l4 * 8];
#pragma unroll
    for (int n = 0; n < 4; ++n)
      bvf[n] = *(const bf16x8*)&Bsm[(wc + n * 16 + l15) * 32 + l4 * 8];
#pragma unroll
    for (int m = 0; m < 4; ++m)
#pragma unroll
      for (int n = 0; n < 4; ++n)
        acc[m][n] = MFMA16(af[m], bvf[n], acc[m][n]);
  }

#pragma unroll
  for (int m = 0; m < 4; ++m) {
#pragma unroll
    for (int n = 0; n < 4; ++n) {
      int row = row0 + wr + m * 16 + l4 * 4;
      int col = col0 + wc + n * 16 + l15;
#pragma unroll
      for (int r = 0; r < 4; ++r) {
        if (EPI == 0) {
          Cb[(size_t)(row + r) * N + col] = f2bf(acc[m][n][r]);
        } else {
          Cf[(size_t)(row + r) * N + col] = acc[m][n][r] + bias[col];
        }
      }
    }
  }
}

template <int EPI>
__global__ __launch_bounds__(256) void gemm_bt(
    const unsigned short* __restrict__ A, const unsigned short* __restrict__ B,
    unsigned short* __restrict__ Cb, float* __restrict__ Cf,
    const float* __restrict__ bias, int N, int K) {
  __shared__ unsigned short Asm[128 * 32];
  __shared__ unsigned short Bsm[128 * 32];
  gemm_core<EPI>(Asm, Bsm, A, B, Cb, Cf, bias, N, K, blockIdx.x);
}

// K-proj (128 blocks) and V^T-proj (128 blocks) fused to fill the GPU.
__global__ __launch_bounds__(256) void gemm_dual(
    const unsigned short* __restrict__ A1, const unsigned short* __restrict__ B1,
    unsigned short* __restrict__ C1,
    const unsigned short* __restrict__ A2, const unsigned short* __restrict__ B2,
    unsigned short* __restrict__ C2, int K) {
  __shared__ unsigned short Asm[128 * 32];
  __shared__ unsigned short Bsm[128 * 32];
  if (blockIdx.x < 128)
    gemm_core<0>(Asm, Bsm, A1, B1, C1, nullptr, nullptr, 512, K, blockIdx.x);
  else
    gemm_core<0>(Asm, Bsm, A2, B2, C2, nullptr, nullptr, 4096, K, blockIdx.x - 128);
}

// ---------------- flash attention v3: 8-wave, 32x32 MFMA, swapped QK^T ----------------
// Block = (b,g) x q-tile pair {j, 63-j}. Waves 0-3: heads 0-3 of qt=j; waves 4-7: qt=63-j.
// K/V double-buffered in LDS (KVBLK=64), XOR-swizzled (pre-swizzled global source).
// S^T = K*Q^T via mfma(Kfrag, Qfrag): lane owns q-col = l&31; k split lane vs lane^32.
__global__ __launch_bounds__(512, 2) void flash_gqa3(
    const unsigned short* __restrict__ Qb, const unsigned short* __restrict__ Kb,
    const unsigned short* __restrict__ VT, unsigned short* __restrict__ Ctx) {
  __shared__ unsigned short Ksm[2][64 * 128];
  __shared__ unsigned short Vsm[2][128 * 64];

  const int tid = threadIdx.x;
  const int wave = tid >> 6, lane = tid & 63;
  const int l31 = lane & 31, hi = lane >> 5;
  const int j = blockIdx.x;   // 0..31
  const int bg = blockIdx.y;  // 0..7
  const int b = bg >> 2, g = bg & 3;
  const int h = (g << 2) | (wave & 3);
  const int qt = (wave < 4) ? j : (63 - j);
  const int q0 = qt << 5;
  const int n_my = ((qt * 32 + 31) >> 6) + 1;
  const int n_tot = (((63 - j) * 32 + 31) >> 6) + 1;

  // Q B-fragments: B[d][q]: lane q=l31, d = ds*16 + hi*8 + j
  bf16x8 qf[8];
  {
    const unsigned short* qp =
        Qb + (size_t)(b * 2048 + q0 + l31) * 2048 + h * 128 + hi * 8;
#pragma unroll
    for (int ds = 0; ds < 8; ++ds) qf[ds] = *(const bf16x8*)(qp + ds * 16);
  }

  // staging sources (pre-swizzled global addr; LDS stays linear — rule #21)
  const int rK0 = tid >> 4, cK = tid & 15, rK1 = rK0 + 32;
  const unsigned short* kS0 =
      Kb + (size_t)(b * 2048 + rK0) * 512 + g * 128 + (cK ^ (rK0 & 7)) * 8;
  const unsigned short* kS1 =
      Kb + (size_t)(b * 2048 + rK1) * 512 + g * 128 + (cK ^ (rK1 & 7)) * 8;
  const int rV0 = tid >> 3, cV = tid & 7, rV1 = rV0 + 64;
  const unsigned short* vS0 =
      VT + (size_t)(g * 128 + rV0) * 4096 + b * 2048 + (cV ^ (rV0 & 7)) * 8;
  const unsigned short* vS1 =
      VT + (size_t)(g * 128 + rV1) * 4096 + b * 2048 + (cV ^ (rV1 & 7)) * 8;

  float m_r = -1e30f, l_r = 0.f;
  f32x16 o0 = {}, o1 = {}, o2 = {}, o3 = {};
  const float scale = 0.08838834764831845f;  // 1/sqrt(128)

#define STAGE(kvn, bufi)                                            \
  {                                                                 \
    unsigned short* kb_ = &Ksm[bufi][0];                            \
    unsigned short* vb_ = &Vsm[bufi][0];                            \
    gload16(kS0 + (size_t)(kvn)*512, kb_ + wave * 512);             \
    gload16(kS1 + (size_t)(kvn)*512, kb_ + 4096 + wave * 512);      \
    gload16(vS0 + (kvn), vb_ + wave * 512);                         \
    gload16(vS1 + (kvn), vb_ + 4096 + wave * 512);                  \
  }

  STAGE(0, 0);
  __syncthreads();

  for (int it = 0; it < n_tot; ++it) {
    const int kv = it << 6;
    if (it + 1 < n_tot) STAGE(kv + 64, (it + 1) & 1);  // prefetch next tile
    if (it < n_my) {
      const char* Kl = (const char*)&Ksm[it & 1][0];
      const char* Vl = (const char*)&Vsm[it & 1][0];
      // ---- S^T = K Q^T : two 32-k tiles over d=128 ----
      f32x16 st0 = {}, st1 = {};
#pragma unroll
      for (int ds = 0; ds < 8; ++ds) {
        const int c = ds * 32 + hi * 16;
        const int by0 = (l31 * 256 + c) ^ ((l31 & 7) << 4);
        const int by1 = ((32 + l31) * 256 + c) ^ ((l31 & 7) << 4);
        bf16x8 kf0 = *(const bf16x8*)(Kl + by0);
        bf16x8 kf1 = *(const bf16x8*)(Kl + by1);
        st0 = MFMA32(kf0, qf[ds], st0);
        st1 = MFMA32(kf1, qf[ds], st1);
      }
      // ---- scale + causal mask (lane owns q = q0+l31; k in regs) ----
      const int q_abs = q0 + l31;
      if (kv + 64 > q0) {
#pragma unroll
        for (int r = 0; r < 16; ++r) {
          const int koff = (r & 3) + 8 * (r >> 2) + 4 * hi;
          st0[r] = (kv + koff <= q_abs) ? st0[r] * scale : -1e30f;
          st1[r] = (kv + 32 + koff <= q_abs) ? st1[r] * scale : -1e30f;
        }
      } else {
#pragma unroll
        for (int r = 0; r < 16; ++r) { st0[r] *= scale; st1[r] *= scale; }
      }
      // ---- in-lane row max + one cross-half swap ----
      float pm = st0[0];
#pragma unroll
      for (int r = 1; r < 16; ++r) pm = fmaxf(pm, st0[r]);
#pragma unroll
      for (int r = 0; r < 16; ++r) pm = fmaxf(pm, st1[r]);
      pm = fmaxf(pm, __shfl_xor(pm, 32));
      const float mn = fmaxf(m_r, pm);
      const float osc = __expf(m_r - mn);
      m_r = mn;
      l_r *= osc;
#pragma unroll
      for (int r = 0; r < 16; ++r) {
        o0[r] *= osc; o1[r] *= osc; o2[r] *= osc; o3[r] *= osc;
      }
      // ---- P = exp(S-m), in-lane sum + one swap ----
      float ps = 0.f;
#pragma unroll
      for (int r = 0; r < 16; ++r) { st0[r] = __expf(st0[r] - mn); ps += st0[r]; }
#pragma unroll
      for (int r = 0; r < 16; ++r) { st1[r] = __expf(st1[r] - mn); ps += st1[r]; }
      ps += __shfl_xor(ps, 32);
      l_r += ps;
      // ---- pack P rows to bf16 pair-words ----
      unsigned w0[8], w1[8];
#pragma unroll
      for (int rp = 0; rp < 8; ++rp) {
        w0[rp] = (unsigned)f2bf(st0[2 * rp]) | ((unsigned)f2bf(st0[2 * rp + 1]) << 16);
        w1[rp] = (unsigned)f2bf(st1[2 * rp]) | ((unsigned)f2bf(st1[2 * rp + 1]) << 16);
      }
      // ---- O^T += V^T P^T : B-frag built in-register (2 shfls per k-slice) ----
#define PV_KS(ks, W)                                                          \
      {                                                                       \
        const int k4 = ((ks) & 1) * 4;                                        \
        unsigned a0 = W[k4], a1 = W[k4 + 1], b0 = W[k4 + 2], b1 = W[k4 + 3];  \
        unsigned q0_ = hi ? a0 : b0, q1_ = hi ? a1 : b1;                      \
        unsigned e0 = (unsigned)__shfl_xor((int)q0_, 32);                     \
        unsigned e1 = (unsigned)__shfl_xor((int)q1_, 32);                     \
        union { u32x4 u; bf16x8 v; } pk;                                      \
        pk.u[0] = hi ? e0 : a0; pk.u[1] = hi ? e1 : a1;                       \
        pk.u[2] = hi ? b0 : e0; pk.u[3] = hi ? b1 : e1;                       \
        const int cb = (ks)*32 + hi * 16;                                     \
        { const int row = l31;      const int by = (row * 128 + cb) ^ ((row & 7) << 4); \
          bf16x8 vf = *(const bf16x8*)(Vl + by); o0 = MFMA32(vf, pk.v, o0); } \
        { const int row = 32 + l31; const int by = (row * 128 + cb) ^ ((row & 7) << 4); \
          bf16x8 vf = *(const bf16x8*)(Vl + by); o1 = MFMA32(vf, pk.v, o1); } \
        { const int row = 64 + l31; const int by = (row * 128 + cb) ^ ((row & 7) << 4); \
          bf16x8 vf = *(const bf16x8*)(Vl + by); o2 = MFMA32(vf, pk.v, o2); } \
        { const int row = 96 + l31; const int by = (row * 128 + cb) ^ ((row & 7) << 4); \
          bf16x8 vf = *(const bf16x8*)(Vl + by); o3 = MFMA32(vf, pk.v, o3); } \
      }
      PV_KS(0, w0) PV_KS(1, w0) PV_KS(2, w1) PV_KS(3, w1)
#undef PV_KS
    }
    __syncthreads();
  }
#undef STAGE

  // ---- finalize: lane owns one q-row; O^T reg (r&3)+8*(r>>2)+4*hi within dt*32 ----
  const float inv = 1.f / l_r;
  unsigned short* cp = Ctx + (size_t)(b * 2048 + q0 + l31) * 2048 + h * 128;
#pragma unroll
  for (int a = 0; a < 4; ++a) {
    ushort4 p0, p1, p2, p3;
    p0.x = f2bf(o0[4 * a + 0] * inv); p0.y = f2bf(o0[4 * a + 1] * inv);
    p0.z = f2bf(o0[4 * a + 2] * inv); p0.w = f2bf(o0[4 * a + 3] * inv);
    p1.x = f2bf(o1[4 * a + 0] * inv); p1.y = f2bf(o1[4 * a + 1] * inv);
    p1.z = f2bf(o1[4 * a + 2] * inv); p1.w = f2bf(o1[4 * a + 3] * inv);
    p2.x = f2bf(o2[4 * a + 0] * inv); p2.y = f2bf(o2[4 * a + 1] * inv);
    p2.z = f2bf(o2[4 * a + 2] * inv); p2.w = f2bf(o2[4 * a + 3] * inv);
    p3.x = f2bf(o3[4 * a + 0] * inv); p3.y = f2bf(o3[4 * a + 1] * inv);
    p3.z = f2bf(o3[4 * a + 2] * inv); p3.w = f2bf(o3[4 * a + 3] * inv);
    const int cc = 8 * a + 4 * hi;
    *(ushort4*)(cp + 0 * 32 + cc) = p0;
    *(ushort4*)(cp + 1 * 32 + cc) = p1;
    *(ushort4*)(cp + 2 * 32 + cc) = p2;
    *(ushort4*)(cp + 3 * 32 + cc) = p3;
  }
}

// ---------------- launch ----------------
extern "C" void kernel_launch(void* const* d_in, const int* in_sizes, int n_in,
                              void* d_out, int out_size, void* d_ws, size_t ws_size,
                              hipStream_t stream) {
  (void)in_sizes; (void)n_in; (void)out_size; (void)ws_size;
  const float* x  = (const float*)d_in[0];
  const float* Wq = (const float*)d_in[1];
  const float* Wk = (const float*)d_in[2];
  const float* Wv = (const float*)d_in[3];
  const float* Wo = (const float*)d_in[4];
  const float* bo = (const float*)d_in[5];
  float* out = (float*)d_out;

  unsigned short* Xb  = (unsigned short*)d_ws;            // [4096,2048]
  unsigned short* WqT = Xb  + (size_t)4096 * 2048;        // [2048,2048]
  unsigned short* WkT = WqT + (size_t)2048 * 2048;        // [512,2048]
  unsigned short* WvT = WkT + (size_t)512 * 2048;         // [512,2048]
  unsigned short* WoT = WvT + (size_t)512 * 2048;         // [2048,2048]
  unsigned short* Qb  = WoT + (size_t)2048 * 2048;        // [4096,2048]
  unsigned short* Kb  = Qb  + (size_t)4096 * 2048;        // [4096,512]
  unsigned short* VTb = Kb  + (size_t)4096 * 512;         // [512,4096]
  unsigned short* Ctx = VTb + (size_t)512 * 4096;         // [4096,2048]

  cast_f32_bf16<<<2048, 256, 0, stream>>>(x, Xb, (4096 * 2048) / 4);
  transpose_cast<<<dim3(64, 64), 256, 0, stream>>>(Wq, WqT, 2048, 2048);
  transpose_cast<<<dim3(16, 64), 256, 0, stream>>>(Wk, WkT, 2048, 512);
  transpose_cast<<<dim3(16, 64), 256, 0, stream>>>(Wv, WvT, 2048, 512);
  transpose_cast<<<dim3(64, 64), 256, 0, stream>>>(Wo, WoT, 2048, 2048);

  // Q = x Wq : [4096,2048]
  gemm_bt<0><<<dim3(512), 256, 0, stream>>>(Xb, WqT, Qb, nullptr, nullptr, 2048, 2048);
  // K = x Wk [4096,512] and V^T = Wv^T x^T [512,4096], fused launch
  gemm_dual<<<dim3(256), 256, 0, stream>>>(Xb, WkT, Kb, WvT, Xb, VTb, 2048);

  flash_gqa3<<<dim3(32, 8), 512, 0, stream>>>(Qb, Kb, VTb, Ctx);

  // out = ctx Wo + bo : [4096,2048] f32
  gemm_bt<1><<<dim3(512), 256, 0, stream>>>(Ctx, WoT, nullptr, out, bo, 2048, 2048);
}

// Round 4
// 217.214 us; speedup vs baseline: 2.6133x; 1.0725x over previous
//
#include <hip/hip_runtime.h>
#include <hip/hip_bf16.h>

typedef short bf16x8 __attribute__((ext_vector_type(8)));
typedef float f32x4 __attribute__((ext_vector_type(4)));
typedef float f32x16 __attribute__((ext_vector_type(16)));
typedef unsigned int u32x4 __attribute__((ext_vector_type(4)));

#define MFMA16(a, b, c) __builtin_amdgcn_mfma_f32_16x16x32_bf16((a), (b), (c), 0, 0, 0)
#define MFMA32(a, b, c) __builtin_amdgcn_mfma_f32_32x32x16_bf16((a), (b), (c), 0, 0, 0)

static __device__ __forceinline__ unsigned short f2bf(float f) {
  union { float f; unsigned u; } v;
  v.f = f;
  unsigned r = (v.u + 0x7FFFu + ((v.u >> 16) & 1u)) >> 16;
  return (unsigned short)r;
}

static __device__ __forceinline__ void gload16(const void* g, void* l) {
  __builtin_amdgcn_global_load_lds(
      (const __attribute__((address_space(1))) unsigned int*)g,
      (__attribute__((address_space(3))) unsigned int*)l, 16, 0, 0);
}

// ---------------- cast f32 -> bf16 (vectorized) ----------------
__global__ __launch_bounds__(256) void cast_f32_bf16(
    const float* __restrict__ src, unsigned short* __restrict__ dst, int n4) {
  int stride = gridDim.x * blockDim.x;
  for (int i = blockIdx.x * blockDim.x + threadIdx.x; i < n4; i += stride) {
    float4 v = reinterpret_cast<const float4*>(src)[i];
    ushort4 o;
    o.x = f2bf(v.x); o.y = f2bf(v.y); o.z = f2bf(v.z); o.w = f2bf(v.w);
    reinterpret_cast<ushort4*>(dst)[i] = o;
  }
}

// ---------------- transpose + cast: src[R][C] f32 -> dst[C][R] bf16 ----------------
__global__ __launch_bounds__(256) void transpose_cast(
    const float* __restrict__ src, unsigned short* __restrict__ dst, int R, int C) {
  __shared__ float tile[32][33];
  int tx = threadIdx.x & 31;
  int ty = threadIdx.x >> 5;  // 0..7
  int r0 = blockIdx.y * 32, c0 = blockIdx.x * 32;
#pragma unroll
  for (int i = 0; i < 32; i += 8)
    tile[ty + i][tx] = src[(size_t)(r0 + ty + i) * C + (c0 + tx)];
  __syncthreads();
#pragma unroll
  for (int i = 0; i < 32; i += 8)
    dst[(size_t)(c0 + ty + i) * R + (r0 + tx)] = f2bf(tile[tx][ty + i]);
}

// ---------------- legacy 128x128 GEMM core (for K/V dual) ----------------
template <int EPI>
static __device__ __forceinline__ void gemm_core(
    unsigned short* Asm, unsigned short* Bsm,
    const unsigned short* __restrict__ A, const unsigned short* __restrict__ B,
    unsigned short* __restrict__ Cb, float* __restrict__ Cf,
    const float* __restrict__ bias, int N, int K, int bid) {
  const int tid = threadIdx.x;
  const int wave = tid >> 6;
  const int lane = tid & 63;
  const int l15 = lane & 15, l4 = lane >> 4;
  const int tilesN = N >> 7;
  const int bm = bid / tilesN, bn = bid % tilesN;
  const int row0 = bm << 7, col0 = bn << 7;
  const int wr = (wave >> 1) << 6, wc = (wave & 1) << 6;

  const int ch0 = wave * 128 + lane;
  const int ch1 = ch0 + 64;
  const int r_a0 = ch0 >> 2, k_a0 = (ch0 & 3) * 8;
  const int r_a1 = ch1 >> 2, k_a1 = (ch1 & 3) * 8;

  f32x4 acc[4][4] = {};

  for (int kt = 0; kt < K; kt += 32) {
    if (kt) __syncthreads();
    gload16(A + (size_t)(row0 + r_a0) * K + kt + k_a0, &Asm[(wave * 2 + 0) * 512]);
    gload16(A + (size_t)(row0 + r_a1) * K + kt + k_a1, &Asm[(wave * 2 + 1) * 512]);
    gload16(B + (size_t)(col0 + r_a0) * K + kt + k_a0, &Bsm[(wave * 2 + 0) * 512]);
    gload16(B + (size_t)(col0 + r_a1) * K + kt + k_a1, &Bsm[(wave * 2 + 1) * 512]);
    __syncthreads();

    bf16x8 af[4], bvf[4];
#pragma unroll
    for (int m = 0; m < 4; ++m)
      af[m] = *(const bf16x8*)&Asm[(wr + m * 16 + l15) * 32 + l4 * 8];
#pragma unroll
    for (int n = 0; n < 4; ++n)
      bvf[n] = *(const bf16x8*)&Bsm[(wc + n * 16 + l15) * 32 + l4 * 8];
#pragma unroll
    for (int m = 0; m < 4; ++m)
#pragma unroll
      for (int n = 0; n < 4; ++n)
        acc[m][n] = MFMA16(af[m], bvf[n], acc[m][n]);
  }

#pragma unroll
  for (int m = 0; m < 4; ++m) {
#pragma unroll
    for (int n = 0; n < 4; ++n) {
      int row = row0 + wr + m * 16 + l4 * 4;
      int col = col0 + wc + n * 16 + l15;
#pragma unroll
      for (int r = 0; r < 4; ++r) {
        if (EPI == 0) {
          Cb[(size_t)(row + r) * N + col] = f2bf(acc[m][n][r]);
        } else {
          Cf[(size_t)(row + r) * N + col] = acc[m][n][r] + bias[col];
        }
      }
    }
  }
}

// K-proj (128 blocks) and V^T-proj (128 blocks) fused to fill the GPU.
__global__ __launch_bounds__(256) void gemm_dual(
    const unsigned short* __restrict__ A1, const unsigned short* __restrict__ B1,
    unsigned short* __restrict__ C1,
    const unsigned short* __restrict__ A2, const unsigned short* __restrict__ B2,
    unsigned short* __restrict__ C2, int K) {
  __shared__ unsigned short Asm[128 * 32];
  __shared__ unsigned short Bsm[128 * 32];
  if (blockIdx.x < 128)
    gemm_core<0>(Asm, Bsm, A1, B1, C1, nullptr, nullptr, 512, K, blockIdx.x);
  else
    gemm_core<0>(Asm, Bsm, A2, B2, C2, nullptr, nullptr, 4096, K, blockIdx.x - 128);
}

// ---------------- 8-phase-style pipelined GEMM: BM=256, BN=128, BK=64 ----------------
// C[M,N] = A[M,K] * B[N,K]^T. 512 thr = 8 waves (4M x 2N), wave tile 64x64.
// Triple-buffered LDS, stage tile t+2 during iter t, counted vmcnt(6),
// raw s_barrier (no vmcnt0 drain), chunk-XOR swizzle both-sides, setprio on MFMA.
template <int EPI>
__global__ __launch_bounds__(512, 2) void gemm8p(
    const unsigned short* __restrict__ A, const unsigned short* __restrict__ B,
    unsigned short* __restrict__ Cb, float* __restrict__ Cf,
    const float* __restrict__ bias, int N, int K) {
  __shared__ unsigned short Al[3][256 * 64];
  __shared__ unsigned short Bl[3][128 * 64];
  const int tid = threadIdx.x;
  const int wave = tid >> 6, lane = tid & 63;
  const int l15 = lane & 15, l4 = lane >> 4;
  const int tilesN = N >> 7;
  const int bm = blockIdx.x / tilesN, bn = blockIdx.x % tilesN;
  const int row0 = bm << 8, col0 = bn << 7;
  const int wr = (wave >> 1) << 6;  // 0,64,128,192
  const int wc = (wave & 1) << 6;   // 0,64

  // staging constants: A tile = 2048 x 16B chunks (4 calls), B = 1024 (2 calls).
  // chunk q -> row = q>>3, in-row chunk c = q&7, swizzled src col c^(row&7).
  const unsigned short* sA[4];
  const unsigned short* sB[2];
#pragma unroll
  for (int i = 0; i < 4; ++i) {
    int q = i * 512 + wave * 64 + lane;
    int r = q >> 3, c = (q & 7) ^ (r & 7);
    sA[i] = A + (size_t)(row0 + r) * K + c * 8;
  }
#pragma unroll
  for (int i = 0; i < 2; ++i) {
    int q = i * 512 + wave * 64 + lane;
    int r = q >> 3, c = (q & 7) ^ (r & 7);
    sB[i] = B + (size_t)(col0 + r) * K + c * 8;
  }

#define STG_H1(t_, bi)                                             \
  { const size_t ko = (size_t)(t_) * 64;                           \
    gload16(sA[0] + ko, &Al[bi][(0 * 512 + wave * 64) * 8]);       \
    gload16(sA[1] + ko, &Al[bi][(1 * 512 + wave * 64) * 8]);       \
    gload16(sB[0] + ko, &Bl[bi][(0 * 512 + wave * 64) * 8]); }
#define STG_H2(t_, bi)                                             \
  { const size_t ko = (size_t)(t_) * 64;                           \
    gload16(sA[2] + ko, &Al[bi][(2 * 512 + wave * 64) * 8]);       \
    gload16(sA[3] + ko, &Al[bi][(3 * 512 + wave * 64) * 8]);       \
    gload16(sB[1] + ko, &Bl[bi][(1 * 512 + wave * 64) * 8]); }

  // read offsets: row byte base + swizzled chunk-in-row
  const int sw = l15 & 7;
  const int c0 = (l4 ^ sw) << 4;
  const int c1 = ((4 + l4) ^ sw) << 4;
  const int rbA = (wr + l15) << 7;
  const int rbB = (wc + l15) << 7;

  f32x4 acc[4][4] = {};
  const int NT = K >> 6;

  STG_H1(0, 0); STG_H2(0, 0);
  STG_H1(1, 1); STG_H2(1, 1);

  int cur = 0;
  for (int t = 0; t < NT; ++t) {
    int sb = cur + 2; if (sb >= 3) sb -= 3;
    if (t + 1 < NT) { asm volatile("s_waitcnt vmcnt(6)" ::: "memory"); }
    else            { asm volatile("s_waitcnt vmcnt(0)" ::: "memory"); }
    __builtin_amdgcn_s_barrier();
    asm volatile("" ::: "memory");
    // ---- P0: read B-frags + A m0,m1; stage half 1 of tile t+2 ----
    const char* Ab = (const char*)&Al[cur][0];
    const char* Bb = (const char*)&Bl[cur][0];
    bf16x8 b0[4], b1[4], aA[2][2], aB[2][2];
#pragma unroll
    for (int n = 0; n < 4; ++n) {
      b0[n] = *(const bf16x8*)(Bb + rbB + n * 2048 + c0);
      b1[n] = *(const bf16x8*)(Bb + rbB + n * 2048 + c1);
    }
#pragma unroll
    for (int m = 0; m < 2; ++m) {
      aA[m][0] = *(const bf16x8*)(Ab + rbA + m * 2048 + c0);
      aA[m][1] = *(const bf16x8*)(Ab + rbA + m * 2048 + c1);
    }
    if (t + 2 < NT) STG_H1(t + 2, sb);
    asm volatile("" ::: "memory");
    __builtin_amdgcn_s_barrier();
    asm volatile("" ::: "memory");
    // ---- P1: MFMA m0,m1; read A m2,m3; stage half 2 ----
    __builtin_amdgcn_s_setprio(1);
#pragma unroll
    for (int m = 0; m < 2; ++m)
#pragma unroll
      for (int n = 0; n < 4; ++n) {
        acc[m][n] = MFMA16(aA[m][0], b0[n], acc[m][n]);
        acc[m][n] = MFMA16(aA[m][1], b1[n], acc[m][n]);
      }
    __builtin_amdgcn_s_setprio(0);
#pragma unroll
    for (int m = 0; m < 2; ++m) {
      aB[m][0] = *(const bf16x8*)(Ab + rbA + (m + 2) * 2048 + c0);
      aB[m][1] = *(const bf16x8*)(Ab + rbA + (m + 2) * 2048 + c1);
    }
    if (t + 2 < NT) STG_H2(t + 2, sb);
    asm volatile("" ::: "memory");
    __builtin_amdgcn_s_barrier();
    asm volatile("" ::: "memory");
    // ---- P2: MFMA m2,m3 ----
    __builtin_amdgcn_s_setprio(1);
#pragma unroll
    for (int m = 0; m < 2; ++m)
#pragma unroll
      for (int n = 0; n < 4; ++n) {
        acc[m + 2][n] = MFMA16(aB[m][0], b0[n], acc[m + 2][n]);
        acc[m + 2][n] = MFMA16(aB[m][1], b1[n], acc[m + 2][n]);
      }
    __builtin_amdgcn_s_setprio(0);
    cur += 1; if (cur >= 3) cur = 0;
  }
#undef STG_H1
#undef STG_H2

#pragma unroll
  for (int m = 0; m < 4; ++m) {
#pragma unroll
    for (int n = 0; n < 4; ++n) {
      int row = row0 + wr + m * 16 + l4 * 4;
      int col = col0 + wc + n * 16 + l15;
#pragma unroll
      for (int r = 0; r < 4; ++r) {
        if (EPI == 0) {
          Cb[(size_t)(row + r) * N + col] = f2bf(acc[m][n][r]);
        } else {
          Cf[(size_t)(row + r) * N + col] = acc[m][n][r] + bias[col];
        }
      }
    }
  }
}

// ---------------- flash attention v3: 8-wave, 32x32 MFMA, swapped QK^T ----------------
__global__ __launch_bounds__(512, 2) void flash_gqa3(
    const unsigned short* __restrict__ Qb, const unsigned short* __restrict__ Kb,
    const unsigned short* __restrict__ VT, unsigned short* __restrict__ Ctx) {
  __shared__ unsigned short Ksm[2][64 * 128];
  __shared__ unsigned short Vsm[2][128 * 64];

  const int tid = threadIdx.x;
  const int wave = tid >> 6, lane = tid & 63;
  const int l31 = lane & 31, hi = lane >> 5;
  const int j = blockIdx.x;   // 0..31
  const int bg = blockIdx.y;  // 0..7
  const int b = bg >> 2, g = bg & 3;
  const int h = (g << 2) | (wave & 3);
  const int qt = (wave < 4) ? j : (63 - j);
  const int q0 = qt << 5;
  const int n_my = ((qt * 32 + 31) >> 6) + 1;
  const int n_tot = (((63 - j) * 32 + 31) >> 6) + 1;

  bf16x8 qf[8];
  {
    const unsigned short* qp =
        Qb + (size_t)(b * 2048 + q0 + l31) * 2048 + h * 128 + hi * 8;
#pragma unroll
    for (int ds = 0; ds < 8; ++ds) qf[ds] = *(const bf16x8*)(qp + ds * 16);
  }

  const int rK0 = tid >> 4, cK = tid & 15, rK1 = rK0 + 32;
  const unsigned short* kS0 =
      Kb + (size_t)(b * 2048 + rK0) * 512 + g * 128 + (cK ^ (rK0 & 7)) * 8;
  const unsigned short* kS1 =
      Kb + (size_t)(b * 2048 + rK1) * 512 + g * 128 + (cK ^ (rK1 & 7)) * 8;
  const int rV0 = tid >> 3, cV = tid & 7, rV1 = rV0 + 64;
  const unsigned short* vS0 =
      VT + (size_t)(g * 128 + rV0) * 4096 + b * 2048 + (cV ^ (rV0 & 7)) * 8;
  const unsigned short* vS1 =
      VT + (size_t)(g * 128 + rV1) * 4096 + b * 2048 + (cV ^ (rV1 & 7)) * 8;

  float m_r = -1e30f, l_r = 0.f;
  f32x16 o0 = {}, o1 = {}, o2 = {}, o3 = {};
  const float scale = 0.08838834764831845f;  // 1/sqrt(128)

#define STAGE(kvn, bufi)                                            \
  {                                                                 \
    unsigned short* kb_ = &Ksm[bufi][0];                            \
    unsigned short* vb_ = &Vsm[bufi][0];                            \
    gload16(kS0 + (size_t)(kvn)*512, kb_ + wave * 512);             \
    gload16(kS1 + (size_t)(kvn)*512, kb_ + 4096 + wave * 512);      \
    gload16(vS0 + (kvn), vb_ + wave * 512);                         \
    gload16(vS1 + (kvn), vb_ + 4096 + wave * 512);                  \
  }

  STAGE(0, 0);
  __syncthreads();

  for (int it = 0; it < n_tot; ++it) {
    const int kv = it << 6;
    if (it + 1 < n_tot) STAGE(kv + 64, (it + 1) & 1);  // prefetch next tile
    if (it < n_my) {
      const char* Kl = (const char*)&Ksm[it & 1][0];
      const char* Vl = (const char*)&Vsm[it & 1][0];
      // ---- S^T = K Q^T ----
      f32x16 st0 = {}, st1 = {};
      __builtin_amdgcn_s_setprio(1);
#pragma unroll
      for (int ds = 0; ds < 8; ++ds) {
        const int c = ds * 32 + hi * 16;
        const int by0 = (l31 * 256 + c) ^ ((l31 & 7) << 4);
        const int by1 = ((32 + l31) * 256 + c) ^ ((l31 & 7) << 4);
        bf16x8 kf0 = *(const bf16x8*)(Kl + by0);
        bf16x8 kf1 = *(const bf16x8*)(Kl + by1);
        st0 = MFMA32(kf0, qf[ds], st0);
        st1 = MFMA32(kf1, qf[ds], st1);
      }
      __builtin_amdgcn_s_setprio(0);
      // ---- scale + causal mask ----
      const int q_abs = q0 + l31;
      if (kv + 64 > q0) {
#pragma unroll
        for (int r = 0; r < 16; ++r) {
          const int koff = (r & 3) + 8 * (r >> 2) + 4 * hi;
          st0[r] = (kv + koff <= q_abs) ? st0[r] * scale : -1e30f;
          st1[r] = (kv + 32 + koff <= q_abs) ? st1[r] * scale : -1e30f;
        }
      } else {
#pragma unroll
        for (int r = 0; r < 16; ++r) { st0[r] *= scale; st1[r] *= scale; }
      }
      // ---- row max ----
      float pm = st0[0];
#pragma unroll
      for (int r = 1; r < 16; ++r) pm = fmaxf(pm, st0[r]);
#pragma unroll
      for (int r = 0; r < 16; ++r) pm = fmaxf(pm, st1[r]);
      pm = fmaxf(pm, __shfl_xor(pm, 32));
      // ---- online softmax update, defer-max (T13) ----
      if (!__all(pm - m_r <= 8.0f)) {
        const float mn = fmaxf(m_r, pm);
        const float osc = __expf(m_r - mn);
        m_r = mn;
        l_r *= osc;
#pragma unroll
        for (int r = 0; r < 16; ++r) {
          o0[r] *= osc; o1[r] *= osc; o2[r] *= osc; o3[r] *= osc;
        }
      }
      float ps = 0.f;
#pragma unroll
      for (int r = 0; r < 16; ++r) { st0[r] = __expf(st0[r] - m_r); ps += st0[r]; }
#pragma unroll
      for (int r = 0; r < 16; ++r) { st1[r] = __expf(st1[r] - m_r); ps += st1[r]; }
      ps += __shfl_xor(ps, 32);
      l_r += ps;
      // ---- pack P rows to bf16 pair-words ----
      unsigned w0[8], w1[8];
#pragma unroll
      for (int rp = 0; rp < 8; ++rp) {
        w0[rp] = (unsigned)f2bf(st0[2 * rp]) | ((unsigned)f2bf(st0[2 * rp + 1]) << 16);
        w1[rp] = (unsigned)f2bf(st1[2 * rp]) | ((unsigned)f2bf(st1[2 * rp + 1]) << 16);
      }
      // ---- O^T += V^T P^T ----
      __builtin_amdgcn_s_setprio(1);
#define PV_KS(ks, W)                                                          \
      {                                                                       \
        const int k4 = ((ks) & 1) * 4;                                        \
        unsigned a0 = W[k4], a1 = W[k4 + 1], b0 = W[k4 + 2], b1 = W[k4 + 3];  \
        unsigned q0_ = hi ? a0 : b0, q1_ = hi ? a1 : b1;                      \
        unsigned e0 = (unsigned)__shfl_xor((int)q0_, 32);                     \
        unsigned e1 = (unsigned)__shfl_xor((int)q1_, 32);                     \
        union { u32x4 u; bf16x8 v; } pk;                                      \
        pk.u[0] = hi ? e0 : a0; pk.u[1] = hi ? e1 : a1;                       \
        pk.u[2] = hi ? b0 : e0; pk.u[3] = hi ? b1 : e1;                       \
        const int cb = (ks)*32 + hi * 16;                                     \
        { const int row = l31;      const int by = (row * 128 + cb) ^ ((row & 7) << 4); \
          bf16x8 vf = *(const bf16x8*)(Vl + by); o0 = MFMA32(vf, pk.v, o0); } \
        { const int row = 32 + l31; const int by = (row * 128 + cb) ^ ((row & 7) << 4); \
          bf16x8 vf = *(const bf16x8*)(Vl + by); o1 = MFMA32(vf, pk.v, o1); } \
        { const int row = 64 + l31; const int by = (row * 128 + cb) ^ ((row & 7) << 4); \
          bf16x8 vf = *(const bf16x8*)(Vl + by); o2 = MFMA32(vf, pk.v, o2); } \
        { const int row = 96 + l31; const int by = (row * 128 + cb) ^ ((row & 7) << 4); \
          bf16x8 vf = *(const bf16x8*)(Vl + by); o3 = MFMA32(vf, pk.v, o3); } \
      }
      PV_KS(0, w0) PV_KS(1, w0) PV_KS(2, w1) PV_KS(3, w1)
#undef PV_KS
      __builtin_amdgcn_s_setprio(0);
    }
    __syncthreads();
  }
#undef STAGE

  const float inv = 1.f / l_r;
  unsigned short* cp = Ctx + (size_t)(b * 2048 + q0 + l31) * 2048 + h * 128;
#pragma unroll
  for (int a = 0; a < 4; ++a) {
    ushort4 p0, p1, p2, p3;
    p0.x = f2bf(o0[4 * a + 0] * inv); p0.y = f2bf(o0[4 * a + 1] * inv);
    p0.z = f2bf(o0[4 * a + 2] * inv); p0.w = f2bf(o0[4 * a + 3] * inv);
    p1.x = f2bf(o1[4 * a + 0] * inv); p1.y = f2bf(o1[4 * a + 1] * inv);
    p1.z = f2bf(o1[4 * a + 2] * inv); p1.w = f2bf(o1[4 * a + 3] * inv);
    p2.x = f2bf(o2[4 * a + 0] * inv); p2.y = f2bf(o2[4 * a + 1] * inv);
    p2.z = f2bf(o2[4 * a + 2] * inv); p2.w = f2bf(o2[4 * a + 3] * inv);
    p3.x = f2bf(o3[4 * a + 0] * inv); p3.y = f2bf(o3[4 * a + 1] * inv);
    p3.z = f2bf(o3[4 * a + 2] * inv); p3.w = f2bf(o3[4 * a + 3] * inv);
    const int cc = 8 * a + 4 * hi;
    *(ushort4*)(cp + 0 * 32 + cc) = p0;
    *(ushort4*)(cp + 1 * 32 + cc) = p1;
    *(ushort4*)(cp + 2 * 32 + cc) = p2;
    *(ushort4*)(cp + 3 * 32 + cc) = p3;
  }
}

// ---------------- launch ----------------
extern "C" void kernel_launch(void* const* d_in, const int* in_sizes, int n_in,
                              void* d_out, int out_size, void* d_ws, size_t ws_size,
                              hipStream_t stream) {
  (void)in_sizes; (void)n_in; (void)out_size; (void)ws_size;
  const float* x  = (const float*)d_in[0];
  const float* Wq = (const float*)d_in[1];
  const float* Wk = (const float*)d_in[2];
  const float* Wv = (const float*)d_in[3];
  const float* Wo = (const float*)d_in[4];
  const float* bo = (const float*)d_in[5];
  float* out = (float*)d_out;

  unsigned short* Xb  = (unsigned short*)d_ws;            // [4096,2048]
  unsigned short* WqT = Xb  + (size_t)4096 * 2048;        // [2048,2048]
  unsigned short* WkT = WqT + (size_t)2048 * 2048;        // [512,2048]
  unsigned short* WvT = WkT + (size_t)512 * 2048;         // [512,2048]
  unsigned short* WoT = WvT + (size_t)512 * 2048;         // [2048,2048]
  unsigned short* Qb  = WoT + (size_t)2048 * 2048;        // [4096,2048]
  unsigned short* Kb  = Qb  + (size_t)4096 * 2048;        // [4096,512]
  unsigned short* VTb = Kb  + (size_t)4096 * 512;         // [512,4096]
  unsigned short* Ctx = VTb + (size_t)512 * 4096;         // [4096,2048]

  cast_f32_bf16<<<2048, 256, 0, stream>>>(x, Xb, (4096 * 2048) / 4);
  transpose_cast<<<dim3(64, 64), 256, 0, stream>>>(Wq, WqT, 2048, 2048);
  transpose_cast<<<dim3(16, 64), 256, 0, stream>>>(Wk, WkT, 2048, 512);
  transpose_cast<<<dim3(16, 64), 256, 0, stream>>>(Wv, WvT, 2048, 512);
  transpose_cast<<<dim3(64, 64), 256, 0, stream>>>(Wo, WoT, 2048, 2048);

  // Q = x Wq : [4096,2048]  (256 blocks of 256x128)
  gemm8p<0><<<dim3(256), 512, 0, stream>>>(Xb, WqT, Qb, nullptr, nullptr, 2048, 2048);
  // K = x Wk [4096,512] and V^T = Wv^T x^T [512,4096], fused launch
  gemm_dual<<<dim3(256), 256, 0, stream>>>(Xb, WkT, Kb, WvT, Xb, VTb, 2048);

  flash_gqa3<<<dim3(32, 8), 512, 0, stream>>>(Qb, Kb, VTb, Ctx);

  // out = ctx Wo + bo : [4096,2048] f32  (256 blocks of 256x128)
  gemm8p<1><<<dim3(256), 512, 0, stream>>>(Ctx, WoT, nullptr, out, bo, 2048, 2048);
}

// Round 6
// 209.415 us; speedup vs baseline: 2.7106x; 1.0372x over previous
//
#include <hip/hip_runtime.h>
#include <hip/hip_bf16.h>

typedef short bf16x8 __attribute__((ext_vector_type(8)));
typedef float f32x4 __attribute__((ext_vector_type(4)));
typedef float f32x16 __attribute__((ext_vector_type(16)));
typedef unsigned int u32x4 __attribute__((ext_vector_type(4)));

#define MFMA16(a, b, c) __builtin_amdgcn_mfma_f32_16x16x32_bf16((a), (b), (c), 0, 0, 0)
#define MFMA32(a, b, c) __builtin_amdgcn_mfma_f32_32x32x16_bf16((a), (b), (c), 0, 0, 0)

static __device__ __forceinline__ unsigned short f2bf(float f) {
  union { float f; unsigned u; } v;
  v.f = f;
  unsigned r = (v.u + 0x7FFFu + ((v.u >> 16) & 1u)) >> 16;
  return (unsigned short)r;
}

static __device__ __forceinline__ void gload16(const void* g, void* l) {
  __builtin_amdgcn_global_load_lds(
      (const __attribute__((address_space(1))) unsigned int*)g,
      (__attribute__((address_space(3))) unsigned int*)l, 16, 0, 0);
}

// ---------------- cast f32 -> bf16 (vectorized) ----------------
__global__ __launch_bounds__(256) void cast_f32_bf16(
    const float* __restrict__ src, unsigned short* __restrict__ dst, int n4) {
  int stride = gridDim.x * blockDim.x;
  for (int i = blockIdx.x * blockDim.x + threadIdx.x; i < n4; i += stride) {
    float4 v = reinterpret_cast<const float4*>(src)[i];
    ushort4 o;
    o.x = f2bf(v.x); o.y = f2bf(v.y); o.z = f2bf(v.z); o.w = f2bf(v.w);
    reinterpret_cast<ushort4*>(dst)[i] = o;
  }
}

// ---------------- transpose + cast: src[R][C] f32 -> dst[C][R] bf16 ----------------
__global__ __launch_bounds__(256) void transpose_cast(
    const float* __restrict__ src, unsigned short* __restrict__ dst, int R, int C) {
  __shared__ float tile[32][33];
  int tx = threadIdx.x & 31;
  int ty = threadIdx.x >> 5;  // 0..7
  int r0 = blockIdx.y * 32, c0 = blockIdx.x * 32;
#pragma unroll
  for (int i = 0; i < 32; i += 8)
    tile[ty + i][tx] = src[(size_t)(r0 + ty + i) * C + (c0 + tx)];
  __syncthreads();
#pragma unroll
  for (int i = 0; i < 32; i += 8)
    dst[(size_t)(c0 + ty + i) * R + (r0 + tx)] = f2bf(tile[tx][ty + i]);
}

// ---------------- legacy 128x128 GEMM core (for K/V dual) ----------------
template <int EPI>
static __device__ __forceinline__ void gemm_core(
    unsigned short* Asm, unsigned short* Bsm,
    const unsigned short* __restrict__ A, const unsigned short* __restrict__ B,
    unsigned short* __restrict__ Cb, float* __restrict__ Cf,
    const float* __restrict__ bias, int N, int K, int bid) {
  const int tid = threadIdx.x;
  const int wave = tid >> 6;
  const int lane = tid & 63;
  const int l15 = lane & 15, l4 = lane >> 4;
  const int tilesN = N >> 7;
  const int bm = bid / tilesN, bn = bid % tilesN;
  const int row0 = bm << 7, col0 = bn << 7;
  const int wr = (wave >> 1) << 6, wc = (wave & 1) << 6;

  const int ch0 = wave * 128 + lane;
  const int ch1 = ch0 + 64;
  const int r_a0 = ch0 >> 2, k_a0 = (ch0 & 3) * 8;
  const int r_a1 = ch1 >> 2, k_a1 = (ch1 & 3) * 8;

  f32x4 acc[4][4] = {};

  for (int kt = 0; kt < K; kt += 32) {
    if (kt) __syncthreads();
    gload16(A + (size_t)(row0 + r_a0) * K + kt + k_a0, &Asm[(wave * 2 + 0) * 512]);
    gload16(A + (size_t)(row0 + r_a1) * K + kt + k_a1, &Asm[(wave * 2 + 1) * 512]);
    gload16(B + (size_t)(col0 + r_a0) * K + kt + k_a0, &Bsm[(wave * 2 + 0) * 512]);
    gload16(B + (size_t)(col0 + r_a1) * K + kt + k_a1, &Bsm[(wave * 2 + 1) * 512]);
    __syncthreads();

    bf16x8 af[4], bvf[4];
#pragma unroll
    for (int m = 0; m < 4; ++m)
      af[m] = *(const bf16x8*)&Asm[(wr + m * 16 + l15) * 32 + l4 * 8];
#pragma unroll
    for (int n = 0; n < 4; ++n)
      bvf[n] = *(const bf16x8*)&Bsm[(wc + n * 16 + l15) * 32 + l4 * 8];
#pragma unroll
    for (int m = 0; m < 4; ++m)
#pragma unroll
      for (int n = 0; n < 4; ++n)
        acc[m][n] = MFMA16(af[m], bvf[n], acc[m][n]);
  }

#pragma unroll
  for (int m = 0; m < 4; ++m) {
#pragma unroll
    for (int n = 0; n < 4; ++n) {
      int row = row0 + wr + m * 16 + l4 * 4;
      int col = col0 + wc + n * 16 + l15;
#pragma unroll
      for (int r = 0; r < 4; ++r) {
        if (EPI == 0) {
          Cb[(size_t)(row + r) * N + col] = f2bf(acc[m][n][r]);
        } else {
          Cf[(size_t)(row + r) * N + col] = acc[m][n][r] + bias[col];
        }
      }
    }
  }
}

// K-proj (128 blocks) and V^T-proj (128 blocks) fused to fill the GPU.
__global__ __launch_bounds__(256) void gemm_dual(
    const unsigned short* __restrict__ A1, const unsigned short* __restrict__ B1,
    unsigned short* __restrict__ C1,
    const unsigned short* __restrict__ A2, const unsigned short* __restrict__ B2,
    unsigned short* __restrict__ C2, int K) {
  __shared__ unsigned short Asm[128 * 32];
  __shared__ unsigned short Bsm[128 * 32];
  if (blockIdx.x < 128)
    gemm_core<0>(Asm, Bsm, A1, B1, C1, nullptr, nullptr, 512, K, blockIdx.x);
  else
    gemm_core<0>(Asm, Bsm, A2, B2, C2, nullptr, nullptr, 4096, K, blockIdx.x - 128);
}

// ---------------- pipelined GEMM: BM=256, BN=128, BK=64 ----------------
template <int EPI>
__global__ __launch_bounds__(512, 2) void gemm8p(
    const unsigned short* __restrict__ A, const unsigned short* __restrict__ B,
    unsigned short* __restrict__ Cb, float* __restrict__ Cf,
    const float* __restrict__ bias, int N, int K) {
  __shared__ unsigned short Al[3][256 * 64];
  __shared__ unsigned short Bl[3][128 * 64];
  const int tid = threadIdx.x;
  const int wave = tid >> 6, lane = tid & 63;
  const int l15 = lane & 15, l4 = lane >> 4;
  const int tilesN = N >> 7;
  const int bm = blockIdx.x / tilesN, bn = blockIdx.x % tilesN;
  const int row0 = bm << 8, col0 = bn << 7;
  const int wr = (wave >> 1) << 6;  // 0,64,128,192
  const int wc = (wave & 1) << 6;   // 0,64

  const unsigned short* sA[4];
  const unsigned short* sB[2];
#pragma unroll
  for (int i = 0; i < 4; ++i) {
    int q = i * 512 + wave * 64 + lane;
    int r = q >> 3, c = (q & 7) ^ (r & 7);
    sA[i] = A + (size_t)(row0 + r) * K + c * 8;
  }
#pragma unroll
  for (int i = 0; i < 2; ++i) {
    int q = i * 512 + wave * 64 + lane;
    int r = q >> 3, c = (q & 7) ^ (r & 7);
    sB[i] = B + (size_t)(col0 + r) * K + c * 8;
  }

#define STG_H1(t_, bi)                                             \
  { const size_t ko = (size_t)(t_) * 64;                           \
    gload16(sA[0] + ko, &Al[bi][(0 * 512 + wave * 64) * 8]);       \
    gload16(sA[1] + ko, &Al[bi][(1 * 512 + wave * 64) * 8]);       \
    gload16(sB[0] + ko, &Bl[bi][(0 * 512 + wave * 64) * 8]); }
#define STG_H2(t_, bi)                                             \
  { const size_t ko = (size_t)(t_) * 64;                           \
    gload16(sA[2] + ko, &Al[bi][(2 * 512 + wave * 64) * 8]);       \
    gload16(sA[3] + ko, &Al[bi][(3 * 512 + wave * 64) * 8]);       \
    gload16(sB[1] + ko, &Bl[bi][(1 * 512 + wave * 64) * 8]); }

  const int sw = l15 & 7;
  const int c0 = (l4 ^ sw) << 4;
  const int c1 = ((4 + l4) ^ sw) << 4;
  const int rbA = (wr + l15) << 7;
  const int rbB = (wc + l15) << 7;

  f32x4 acc[4][4] = {};
  const int NT = K >> 6;

  STG_H1(0, 0); STG_H2(0, 0);
  STG_H1(1, 1); STG_H2(1, 1);

  int cur = 0;
  for (int t = 0; t < NT; ++t) {
    int sb = cur + 2; if (sb >= 3) sb -= 3;
    if (t + 1 < NT) { asm volatile("s_waitcnt vmcnt(6)" ::: "memory"); }
    else            { asm volatile("s_waitcnt vmcnt(0)" ::: "memory"); }
    __builtin_amdgcn_s_barrier();
    asm volatile("" ::: "memory");
    const char* Ab = (const char*)&Al[cur][0];
    const char* Bb = (const char*)&Bl[cur][0];
    bf16x8 b0[4], b1[4], aA[2][2], aB[2][2];
#pragma unroll
    for (int n = 0; n < 4; ++n) {
      b0[n] = *(const bf16x8*)(Bb + rbB + n * 2048 + c0);
      b1[n] = *(const bf16x8*)(Bb + rbB + n * 2048 + c1);
    }
#pragma unroll
    for (int m = 0; m < 2; ++m) {
      aA[m][0] = *(const bf16x8*)(Ab + rbA + m * 2048 + c0);
      aA[m][1] = *(const bf16x8*)(Ab + rbA + m * 2048 + c1);
    }
    if (t + 2 < NT) STG_H1(t + 2, sb);
    asm volatile("" ::: "memory");
    __builtin_amdgcn_s_barrier();
    asm volatile("" ::: "memory");
    __builtin_amdgcn_s_setprio(1);
#pragma unroll
    for (int m = 0; m < 2; ++m)
#pragma unroll
      for (int n = 0; n < 4; ++n) {
        acc[m][n] = MFMA16(aA[m][0], b0[n], acc[m][n]);
        acc[m][n] = MFMA16(aA[m][1], b1[n], acc[m][n]);
      }
    __builtin_amdgcn_s_setprio(0);
#pragma unroll
    for (int m = 0; m < 2; ++m) {
      aB[m][0] = *(const bf16x8*)(Ab + rbA + (m + 2) * 2048 + c0);
      aB[m][1] = *(const bf16x8*)(Ab + rbA + (m + 2) * 2048 + c1);
    }
    if (t + 2 < NT) STG_H2(t + 2, sb);
    asm volatile("" ::: "memory");
    __builtin_amdgcn_s_barrier();
    asm volatile("" ::: "memory");
    __builtin_amdgcn_s_setprio(1);
#pragma unroll
    for (int m = 0; m < 2; ++m)
#pragma unroll
      for (int n = 0; n < 4; ++n) {
        acc[m + 2][n] = MFMA16(aB[m][0], b0[n], acc[m + 2][n]);
        acc[m + 2][n] = MFMA16(aB[m][1], b1[n], acc[m + 2][n]);
      }
    __builtin_amdgcn_s_setprio(0);
    cur += 1; if (cur >= 3) cur = 0;
  }
#undef STG_H1
#undef STG_H2

#pragma unroll
  for (int m = 0; m < 4; ++m) {
#pragma unroll
    for (int n = 0; n < 4; ++n) {
      int row = row0 + wr + m * 16 + l4 * 4;
      int col = col0 + wc + n * 16 + l15;
#pragma unroll
      for (int r = 0; r < 4; ++r) {
        if (EPI == 0) {
          Cb[(size_t)(row + r) * N + col] = f2bf(acc[m][n][r]);
        } else {
          Cf[(size_t)(row + r) * N + col] = acc[m][n][r] + bias[col];
        }
      }
    }
  }
}

// ---------------- flash attention v4: kv-split + sequential q-tiles ----------------
// Block = (pair j, (b,g)). 8 waves: head = wave&3, kv-partition = wave>>2.
// Two sequential phases: qt = 63-j, then qt = j. Per phase, partition p handles
// kv tiles t = 2r+p; states merged through LDS at phase end.
// LDS: 2 bufs x 2 parts x (K 16KB + V 16KB) = 128 KiB; merge scratch aliases it
// (indexed by BLOCK-LOCAL head wave&3 — global h overflows the 128 KiB block).
__global__ __launch_bounds__(512, 1) void flash_gqa4(
    const unsigned short* __restrict__ Qb, const unsigned short* __restrict__ Kb,
    const unsigned short* __restrict__ VT, unsigned short* __restrict__ Ctx) {
  __shared__ unsigned short Sm[65536];  // 128 KiB

  const int tid = threadIdx.x;
  const int wave = tid >> 6, lane = tid & 63;
  const int l31 = lane & 31, hi = lane >> 5;
  const int j = blockIdx.x;   // 0..31
  const int bg = blockIdx.y;  // 0..7
  const int b = bg >> 2, g = bg & 3;
  const int hl = wave & 3;        // block-local head
  const int h = (g << 2) | hl;    // global head
  const int part = wave >> 2;

  // staging sources (pre-swizzled global addr; LDS linear — rule #21)
  const int rK0 = tid >> 4, cK = tid & 15, rK1 = rK0 + 32;
  const unsigned short* kS0 =
      Kb + (size_t)(b * 2048 + rK0) * 512 + g * 128 + (cK ^ (rK0 & 7)) * 8;
  const unsigned short* kS1 =
      Kb + (size_t)(b * 2048 + rK1) * 512 + g * 128 + (cK ^ (rK1 & 7)) * 8;
  const int rV0 = tid >> 3, cV = tid & 7, rV1 = rV0 + 64;
  const unsigned short* vS0 =
      VT + (size_t)(g * 128 + rV0) * 4096 + b * 2048 + (cV ^ (rV0 & 7)) * 8;
  const unsigned short* vS1 =
      VT + (size_t)(g * 128 + rV1) * 4096 + b * 2048 + (cV ^ (rV1 & 7)) * 8;

  const float scale = 0.08838834764831845f;  // 1/sqrt(128)

// stage K/V tile t_ (phase-local) into part slot (t_&1) of buffer bi
#define STAGE4(t_, bi)                                                   \
  {                                                                      \
    unsigned short* kb_ = Sm + (bi)*32768 + ((t_)&1) * 16384;            \
    unsigned short* vb_ = kb_ + 8192;                                    \
    const size_t ko_ = (size_t)(t_) * 64;                                \
    gload16(kS0 + ko_ * 512, kb_ + wave * 512);                          \
    gload16(kS1 + ko_ * 512, kb_ + 4096 + wave * 512);                   \
    gload16(vS0 + ko_, vb_ + wave * 512);                                \
    gload16(vS1 + ko_, vb_ + 4096 + wave * 512);                         \
  }

  for (int ph = 0; ph < 2; ++ph) {
    const int qt = ph ? j : (63 - j);
    const int q0 = qt << 5;
    const int T = (qt >> 1) + 1;       // kv tiles needed
    const int R = (T + 1) >> 1;        // rounds (2 tiles/round)

    // Q B-fragments for this q-tile
    bf16x8 qf[8];
    {
      const unsigned short* qp =
          Qb + (size_t)(b * 2048 + q0 + l31) * 2048 + h * 128 + hi * 8;
#pragma unroll
      for (int ds = 0; ds < 8; ++ds) qf[ds] = *(const bf16x8*)(qp + ds * 16);
    }

    float m_r = -1e30f, l_r = 0.f;
    f32x16 o0 = {}, o1 = {}, o2 = {}, o3 = {};

    STAGE4(0, 0);
    if (1 < T) STAGE4(1, 0);
    __syncthreads();

    for (int r = 0; r < R; ++r) {
      const int buf = r & 1;
      if (r + 1 < R) {
        STAGE4(2 * r + 2, buf ^ 1);
        if (2 * r + 3 < T) STAGE4(2 * r + 3, buf ^ 1);
      }
      const int t = 2 * r + part;
      if (t < T) {
        const int kv = t << 6;
        const char* Kl = (const char*)Sm + buf * 65536 + part * 32768;
        const char* Vl = Kl + 16384;
        // ---- S^T = K Q^T ----
        f32x16 st0 = {}, st1 = {};
        __builtin_amdgcn_s_setprio(1);
#pragma unroll
        for (int ds = 0; ds < 8; ++ds) {
          const int c = ds * 32 + hi * 16;
          const int by0 = (l31 * 256 + c) ^ ((l31 & 7) << 4);
          const int by1 = ((32 + l31) * 256 + c) ^ ((l31 & 7) << 4);
          bf16x8 kf0 = *(const bf16x8*)(Kl + by0);
          bf16x8 kf1 = *(const bf16x8*)(Kl + by1);
          st0 = MFMA32(kf0, qf[ds], st0);
          st1 = MFMA32(kf1, qf[ds], st1);
        }
        __builtin_amdgcn_s_setprio(0);
        // ---- scale + causal mask ----
        const int q_abs = q0 + l31;
        if (kv + 64 > q0) {
#pragma unroll
          for (int rr = 0; rr < 16; ++rr) {
            const int koff = (rr & 3) + 8 * (rr >> 2) + 4 * hi;
            st0[rr] = (kv + koff <= q_abs) ? st0[rr] * scale : -1e30f;
            st1[rr] = (kv + 32 + koff <= q_abs) ? st1[rr] * scale : -1e30f;
          }
        } else {
#pragma unroll
          for (int rr = 0; rr < 16; ++rr) { st0[rr] *= scale; st1[rr] *= scale; }
        }
        // ---- row max ----
        float pm = st0[0];
#pragma unroll
        for (int rr = 1; rr < 16; ++rr) pm = fmaxf(pm, st0[rr]);
#pragma unroll
        for (int rr = 0; rr < 16; ++rr) pm = fmaxf(pm, st1[rr]);
        pm = fmaxf(pm, __shfl_xor(pm, 32));
        // ---- online softmax update, defer-max (T13) ----
        if (!__all(pm - m_r <= 8.0f)) {
          const float mn = fmaxf(m_r, pm);
          const float osc = __expf(m_r - mn);
          m_r = mn;
          l_r *= osc;
#pragma unroll
          for (int rr = 0; rr < 16; ++rr) {
            o0[rr] *= osc; o1[rr] *= osc; o2[rr] *= osc; o3[rr] *= osc;
          }
        }
        float ps = 0.f;
#pragma unroll
        for (int rr = 0; rr < 16; ++rr) { st0[rr] = __expf(st0[rr] - m_r); ps += st0[rr]; }
#pragma unroll
        for (int rr = 0; rr < 16; ++rr) { st1[rr] = __expf(st1[rr] - m_r); ps += st1[rr]; }
        ps += __shfl_xor(ps, 32);
        l_r += ps;
        // ---- pack P rows to bf16 pair-words ----
        unsigned w0[8], w1[8];
#pragma unroll
        for (int rp = 0; rp < 8; ++rp) {
          w0[rp] = (unsigned)f2bf(st0[2 * rp]) | ((unsigned)f2bf(st0[2 * rp + 1]) << 16);
          w1[rp] = (unsigned)f2bf(st1[2 * rp]) | ((unsigned)f2bf(st1[2 * rp + 1]) << 16);
        }
        // ---- O^T += V^T P^T ----
        __builtin_amdgcn_s_setprio(1);
#define PV_KS(ks, W)                                                          \
        {                                                                     \
          const int k4 = ((ks) & 1) * 4;                                      \
          unsigned a0 = W[k4], a1 = W[k4 + 1], b0 = W[k4 + 2], b1 = W[k4 + 3];\
          unsigned q0_ = hi ? a0 : b0, q1_ = hi ? a1 : b1;                    \
          unsigned e0 = (unsigned)__shfl_xor((int)q0_, 32);                   \
          unsigned e1 = (unsigned)__shfl_xor((int)q1_, 32);                   \
          union { u32x4 u; bf16x8 v; } pk;                                    \
          pk.u[0] = hi ? e0 : a0; pk.u[1] = hi ? e1 : a1;                     \
          pk.u[2] = hi ? b0 : e0; pk.u[3] = hi ? b1 : e1;                     \
          const int cb = (ks)*32 + hi * 16;                                   \
          { const int row = l31;      const int by = (row * 128 + cb) ^ ((row & 7) << 4); \
            bf16x8 vf = *(const bf16x8*)(Vl + by); o0 = MFMA32(vf, pk.v, o0); } \
          { const int row = 32 + l31; const int by = (row * 128 + cb) ^ ((row & 7) << 4); \
            bf16x8 vf = *(const bf16x8*)(Vl + by); o1 = MFMA32(vf, pk.v, o1); } \
          { const int row = 64 + l31; const int by = (row * 128 + cb) ^ ((row & 7) << 4); \
            bf16x8 vf = *(const bf16x8*)(Vl + by); o2 = MFMA32(vf, pk.v, o2); } \
          { const int row = 96 + l31; const int by = (row * 128 + cb) ^ ((row & 7) << 4); \
            bf16x8 vf = *(const bf16x8*)(Vl + by); o3 = MFMA32(vf, pk.v, o3); } \
        }
        PV_KS(0, w0) PV_KS(1, w0) PV_KS(2, w1) PV_KS(3, w1)
#undef PV_KS
        __builtin_amdgcn_s_setprio(0);
      }
      __syncthreads();
    }

    // ---- merge the two kv-partitions through LDS scratch ----
    // scratch: per local head 4352 f32 (17 KiB), total 4*17.4 KB < 128 KiB.
    float* F = (float*)Sm;
    float* sc = F + (size_t)hl * 4352 + lane * 68;  // 68-f32 stride, 16B-aligned
    if (part == 1) {
      union { f32x16 v; f32x4 q[4]; } u;
      u.v = o0;
#pragma unroll
      for (int k = 0; k < 4; ++k) *(f32x4*)(sc + 0 + 4 * k) = u.q[k];
      u.v = o1;
#pragma unroll
      for (int k = 0; k < 4; ++k) *(f32x4*)(sc + 16 + 4 * k) = u.q[k];
      u.v = o2;
#pragma unroll
      for (int k = 0; k < 4; ++k) *(f32x4*)(sc + 32 + 4 * k) = u.q[k];
      u.v = o3;
#pragma unroll
      for (int k = 0; k < 4; ++k) *(f32x4*)(sc + 48 + 4 * k) = u.q[k];
      sc[64] = m_r;
      sc[65] = l_r;
    }
    __syncthreads();
    if (part == 0) {
      const float m2 = sc[64], l2 = sc[65];
      const float mm = fmaxf(m_r, m2);
      const float fa = __expf(m_r - mm), fb = __expf(m2 - mm);
      const float inv = 1.f / (l_r * fa + l2 * fb);
      unsigned short* cp = Ctx + (size_t)(b * 2048 + q0 + l31) * 2048 + h * 128;
#pragma unroll
      for (int a = 0; a < 4; ++a) {
        f32x4 u0 = *(const f32x4*)(sc + 0 + 4 * a);
        f32x4 u1 = *(const f32x4*)(sc + 16 + 4 * a);
        f32x4 u2 = *(const f32x4*)(sc + 32 + 4 * a);
        f32x4 u3 = *(const f32x4*)(sc + 48 + 4 * a);
        ushort4 p0, p1, p2, p3;
        p0.x = f2bf((o0[4 * a + 0] * fa + u0[0] * fb) * inv);
        p0.y = f2bf((o0[4 * a + 1] * fa + u0[1] * fb) * inv);
        p0.z = f2bf((o0[4 * a + 2] * fa + u0[2] * fb) * inv);
        p0.w = f2bf((o0[4 * a + 3] * fa + u0[3] * fb) * inv);
        p1.x = f2bf((o1[4 * a + 0] * fa + u1[0] * fb) * inv);
        p1.y = f2bf((o1[4 * a + 1] * fa + u1[1] * fb) * inv);
        p1.z = f2bf((o1[4 * a + 2] * fa + u1[2] * fb) * inv);
        p1.w = f2bf((o1[4 * a + 3] * fa + u1[3] * fb) * inv);
        p2.x = f2bf((o2[4 * a + 0] * fa + u2[0] * fb) * inv);
        p2.y = f2bf((o2[4 * a + 1] * fa + u2[1] * fb) * inv);
        p2.z = f2bf((o2[4 * a + 2] * fa + u2[2] * fb) * inv);
        p2.w = f2bf((o2[4 * a + 3] * fa + u2[3] * fb) * inv);
        p3.x = f2bf((o3[4 * a + 0] * fa + u3[0] * fb) * inv);
        p3.y = f2bf((o3[4 * a + 1] * fa + u3[1] * fb) * inv);
        p3.z = f2bf((o3[4 * a + 2] * fa + u3[2] * fb) * inv);
        p3.w = f2bf((o3[4 * a + 3] * fa + u3[3] * fb) * inv);
        const int cc = 8 * a + 4 * hi;
        *(ushort4*)(cp + 0 * 32 + cc) = p0;
        *(ushort4*)(cp + 1 * 32 + cc) = p1;
        *(ushort4*)(cp + 2 * 32 + cc) = p2;
        *(ushort4*)(cp + 3 * 32 + cc) = p3;
      }
    }
    __syncthreads();  // scratch free before next phase's staging
  }
#undef STAGE4
}

// ---------------- launch ----------------
extern "C" void kernel_launch(void* const* d_in, const int* in_sizes, int n_in,
                              void* d_out, int out_size, void* d_ws, size_t ws_size,
                              hipStream_t stream) {
  (void)in_sizes; (void)n_in; (void)out_size; (void)ws_size;
  const float* x  = (const float*)d_in[0];
  const float* Wq = (const float*)d_in[1];
  const float* Wk = (const float*)d_in[2];
  const float* Wv = (const float*)d_in[3];
  const float* Wo = (const float*)d_in[4];
  const float* bo = (const float*)d_in[5];
  float* out = (float*)d_out;

  unsigned short* Xb  = (unsigned short*)d_ws;            // [4096,2048]
  unsigned short* WqT = Xb  + (size_t)4096 * 2048;        // [2048,2048]
  unsigned short* WkT = WqT + (size_t)2048 * 2048;        // [512,2048]
  unsigned short* WvT = WkT + (size_t)512 * 2048;         // [512,2048]
  unsigned short* WoT = WvT + (size_t)512 * 2048;         // [2048,2048]
  unsigned short* Qb  = WoT + (size_t)2048 * 2048;        // [4096,2048]
  unsigned short* Kb  = Qb  + (size_t)4096 * 2048;        // [4096,512]
  unsigned short* VTb = Kb  + (size_t)4096 * 512;         // [512,4096]
  unsigned short* Ctx = VTb + (size_t)512 * 4096;         // [4096,2048]

  cast_f32_bf16<<<2048, 256, 0, stream>>>(x, Xb, (4096 * 2048) / 4);
  transpose_cast<<<dim3(64, 64), 256, 0, stream>>>(Wq, WqT, 2048, 2048);
  transpose_cast<<<dim3(16, 64), 256, 0, stream>>>(Wk, WkT, 2048, 512);
  transpose_cast<<<dim3(16, 64), 256, 0, stream>>>(Wv, WvT, 2048, 512);
  transpose_cast<<<dim3(64, 64), 256, 0, stream>>>(Wo, WoT, 2048, 2048);

  // Q = x Wq : [4096,2048]  (256 blocks of 256x128)
  gemm8p<0><<<dim3(256), 512, 0, stream>>>(Xb, WqT, Qb, nullptr, nullptr, 2048, 2048);
  // K = x Wk [4096,512] and V^T = Wv^T x^T [512,4096], fused launch
  gemm_dual<<<dim3(256), 256, 0, stream>>>(Xb, WkT, Kb, WvT, Xb, VTb, 2048);

  flash_gqa4<<<dim3(32, 8), 512, 0, stream>>>(Qb, Kb, VTb, Ctx);

  // out = ctx Wo + bo : [4096,2048] f32  (256 blocks of 256x128)
  gemm8p<1><<<dim3(256), 512, 0, stream>>>(Ctx, WoT, nullptr, out, bo, 2048, 2048);
}